// Round 2
// baseline (1988.682 us; speedup 1.0000x reference)
//
#include <hip/hip_runtime.h>

#define DEV __device__ __forceinline__

typedef __attribute__((ext_vector_type(8))) short bf16x8;
typedef __attribute__((ext_vector_type(4))) float f32x4;
typedef unsigned short u16;
typedef __attribute__((address_space(1))) const void* gvp;
typedef __attribute__((address_space(3))) void* svp;

DEV u16 f2bf(float f){
  unsigned u = __float_as_uint(f);
  u = (u + 0x7FFFu + ((u >> 16) & 1u)) >> 16;
  return (u16)u;
}
DEV float bf2f(u16 v){ return __uint_as_float(((unsigned)v) << 16); }

// ---------------- convert f32 -> bf16 ----------------
__global__ void k_cvt(const float* __restrict__ s, u16* __restrict__ d, int n){
  int i = blockIdx.x * 256 + threadIdx.x;
  if (i < n) d[i] = f2bf(s[i]);
}

// ---------------- concat 3 bias vectors (1024 each) ----------------
__global__ void k_cat3(const float* __restrict__ a, const float* __restrict__ b,
                       const float* __restrict__ c, float* __restrict__ o){
  int i = blockIdx.x * 256 + threadIdx.x;
  if (i < 1024){ o[i] = a[i]; o[1024 + i] = b[i]; o[2048 + i] = c[i]; }
}

// ---------------- layernorm over D=1024, bf16 out ----------------
__global__ __launch_bounds__(256) void k_ln(const float* __restrict__ x, const float* __restrict__ w,
                                            const float* __restrict__ b, u16* __restrict__ y){
  const int row = blockIdx.x;
  const int tid = threadIdx.x;
  const float4 v = ((const float4*)(x + (size_t)row * 1024))[tid];
  float s1 = v.x + v.y + v.z + v.w;
  float s2 = v.x*v.x + v.y*v.y + v.z*v.z + v.w*v.w;
  #pragma unroll
  for (int o = 32; o > 0; o >>= 1){ s1 += __shfl_down(s1, o); s2 += __shfl_down(s2, o); }
  __shared__ float r1[4], r2[4];
  __shared__ float mu_s, rs_s;
  const int wv = tid >> 6;
  if ((tid & 63) == 0){ r1[wv] = s1; r2[wv] = s2; }
  __syncthreads();
  if (tid == 0){
    float t1 = r1[0]+r1[1]+r1[2]+r1[3], t2 = r2[0]+r2[1]+r2[2]+r2[3];
    float mu = t1 * (1.0f/1024.0f);
    float var = t2 * (1.0f/1024.0f) - mu*mu;
    mu_s = mu; rs_s = rsqrtf(var + 1e-6f);
  }
  __syncthreads();
  const float mu = mu_s, rs = rs_s;
  const float4 wv4 = ((const float4*)w)[tid];
  const float4 bv4 = ((const float4*)b)[tid];
  ushort4 o4;
  o4.x = f2bf((v.x-mu)*rs*wv4.x + bv4.x);
  o4.y = f2bf((v.y-mu)*rs*wv4.y + bv4.y);
  o4.z = f2bf((v.z-mu)*rs*wv4.z + bv4.z);
  o4.w = f2bf((v.w-mu)*rs*wv4.w + bv4.w);
  ((ushort4*)(y + (size_t)row*1024))[tid] = o4;
}

// ---------------- 256x256 tile, BK=32, 3-stage pipelined bf16 MFMA GEMM ----------------
// C = A(MxK) * Bw(NxK)^T + bias
// MODE 0: bf16 store. MODE 1: gelu then bf16 store. MODE 2: f32 out[off] += v
template<int MODE>
__launch_bounds__(512, 2)
__global__ void k_gemm2(const u16* __restrict__ A, const u16* __restrict__ Bw,
                        const float* __restrict__ bias, void* __restrict__ out,
                        int M, int N, int K)
{
  __shared__ __align__(16) u16 LAs[3][8192];   // 3 x (256 rows x 32 k) bf16 = 48KB
  __shared__ __align__(16) u16 LBs[3][8192];   // 48KB
  const int tid = threadIdx.x;
  const int wave = tid >> 6, lane = tid & 63;
  const int l15 = lane & 15, l4 = lane >> 4;
  const int wr = wave >> 2, wc = wave & 3;     // 2 x 4 wave grid; per-wave out 128x64
  const int bn = blockIdx.x, bm = blockIdx.y;
  const int NT = K >> 5;                       // K-tiles of 32
  (void)M;

  // ---- staging geometry (linear LDS dest; inverse-swizzled global source) ----
  // instr i in {0,1}: LDS row = wave*32 + i*16 + (lane>>2), chunk16B = lane&3
  // source chunk = (lane&3) ^ ((row>>1)&3) = (lane&3) ^ ((lane>>3)&3)  (wave/i drop out mod 4)
  const int srow = wave*32 + (lane>>2);
  const int schunk = ((lane&3) ^ ((lane>>3)&3)) * 8;      // u16 units
  const u16* gA = A  + ((size_t)bm*256 + srow) * K + schunk;
  const u16* gB = Bw + ((size_t)bn*256 + srow) * K + schunk;
  const size_t g16 = (size_t)16 * K;                      // +16 rows for instr 1
  const int ldst = wave * 1024;                           // u16; +512 for instr 1

  // ---- swizzled ds_read offsets (u16 units); row stride 32 u16 = 64B ----
  // frag row r: byte ^= (((r>>1)&3)<<4); (r>>1)&3 == (l15>>1)&3 for all frags
  const int sw4 = (l4 ^ ((l15 >> 1) & 3)) * 8;
  const int aoff = (wr*128 + l15) * 32 + sw4;             // + m*512 per m-frag
  const int boff = (wc*64  + l15) * 32 + sw4;             // + n*512 per n-frag

  f32x4 acc[8][4];
  const f32x4 z4 = {0.f, 0.f, 0.f, 0.f};
  #pragma unroll
  for (int m = 0; m < 8; ++m)
    #pragma unroll
    for (int n = 0; n < 4; ++n) acc[m][n] = z4;

#define STAGE2(bufi, tki) do{ \
    const u16* ga_ = gA + (size_t)(tki) * 32; \
    const u16* gb_ = gB + (size_t)(tki) * 32; \
    u16* la_ = &LAs[bufi][ldst]; \
    u16* lb_ = &LBs[bufi][ldst]; \
    __builtin_amdgcn_global_load_lds((gvp)ga_,        (svp)la_,        16, 0, 0); \
    __builtin_amdgcn_global_load_lds((gvp)(ga_ + g16),(svp)(la_ + 512),16, 0, 0); \
    __builtin_amdgcn_global_load_lds((gvp)gb_,        (svp)lb_,        16, 0, 0); \
    __builtin_amdgcn_global_load_lds((gvp)(gb_ + g16),(svp)(lb_ + 512),16, 0, 0); \
  }while(0)

  // prologue: stage t=0 and t=1; wait for t=0 (leave t=1's 4 loads in flight)
  STAGE2(0, 0);
  STAGE2(1, 1);
  asm volatile("s_waitcnt vmcnt(4)" ::: "memory");
  __builtin_amdgcn_s_barrier();
  asm volatile("" ::: "memory");

  int cur = 0, nxt = 2;
  for (int t = 0; t < NT; ++t){
    if (t + 2 < NT) STAGE2(nxt, t + 2);      // buf[(t+2)%3]: disjoint from buf[t%3], buf[(t+1)%3]
    const u16* bA = &LAs[cur][0];
    const u16* bB = &LBs[cur][0];
    bf16x8 fb[4], fa[4];
    #pragma unroll
    for (int n = 0; n < 4; ++n) fb[n] = *(const bf16x8*)(bB + boff + n*512);
    #pragma unroll
    for (int m = 0; m < 4; ++m) fa[m] = *(const bf16x8*)(bA + aoff + m*512);
    __builtin_amdgcn_s_setprio(1);
    #pragma unroll
    for (int m = 0; m < 4; ++m)
      #pragma unroll
      for (int n = 0; n < 4; ++n)
        acc[m][n] = __builtin_amdgcn_mfma_f32_16x16x32_bf16(fa[m], fb[n], acc[m][n], 0, 0, 0);
    __builtin_amdgcn_s_setprio(0);
    #pragma unroll
    for (int m = 0; m < 4; ++m) fa[m] = *(const bf16x8*)(bA + aoff + (m+4)*512);
    __builtin_amdgcn_s_setprio(1);
    #pragma unroll
    for (int m = 0; m < 4; ++m)
      #pragma unroll
      for (int n = 0; n < 4; ++n)
        acc[m+4][n] = __builtin_amdgcn_mfma_f32_16x16x32_bf16(fa[m], fb[n], acc[m+4][n], 0, 0, 0);
    __builtin_amdgcn_s_setprio(0);
    // counted-vmcnt pipeline barrier: ensure t+1's loads landed; keep t+2's (newest 4) in flight
    if (t + 2 < NT){
      asm volatile("s_waitcnt vmcnt(4)" ::: "memory");
    } else if (t + 1 < NT){
      asm volatile("s_waitcnt vmcnt(0)" ::: "memory");
    }
    if (t + 1 < NT){
      __builtin_amdgcn_s_barrier();
      asm volatile("" ::: "memory");
    }
    cur = (cur == 2) ? 0 : cur + 1;
    nxt = (nxt == 2) ? 0 : nxt + 1;
  }
#undef STAGE2

  #pragma unroll
  for (int m = 0; m < 8; ++m){
    const int gr0 = bm*256 + wr*128 + m*16 + l4*4;
    #pragma unroll
    for (int n = 0; n < 4; ++n){
      const int gc = bn*256 + wc*64 + n*16 + l15;
      const float bv = bias[gc];
      #pragma unroll
      for (int r2 = 0; r2 < 4; ++r2){
        const size_t off = (size_t)(gr0 + r2) * N + gc;
        float v = acc[m][n][r2] + bv;
        if (MODE == 0){
          ((u16*)out)[off] = f2bf(v);
        } else if (MODE == 1){
          const float a = 0.7978845608028654f * (v + 0.044715f * v * v * v);
          const float e = __expf(2.0f * a);
          const float th = (e - 1.0f) / (e + 1.0f);
          ((u16*)out)[off] = f2bf(0.5f * v * (1.0f + th));
        } else {
          float* op = (float*)out;
          op[off] += v;
        }
      }
    }
  }
}

// ---------------- transpose (B,L,ld) slice -> (B,H,64,L) per (b,h), bf16 ----------------
__global__ __launch_bounds__(256) void k_tr(const u16* __restrict__ Q, u16* __restrict__ Qt, int ld){
  __shared__ u16 Ls[64][65];
  const int tid = threadIdx.x;
  const int bh = blockIdx.y;
  const int b = bh >> 4, h = bh & 15;
  const int l0 = blockIdx.x * 64;
  #pragma unroll
  for (int i = 0; i < 16; ++i){
    const int id = i*256 + tid;
    const int lr = id >> 6, dc = id & 63;
    Ls[lr][dc] = Q[((size_t)b*4096 + l0 + lr)*ld + h*64 + dc];
  }
  __syncthreads();
  #pragma unroll
  for (int i = 0; i < 16; ++i){
    const int id = i*256 + tid;
    const int dr = id >> 6, lc = id & 63;
    Qt[((size_t)bh*64 + dr)*4096 + l0 + lc] = Ls[lc][dr];
  }
}

// ---------------- in-LDS radix-2 DIT FFT, N=4096, 256 threads ----------------
DEV void fft4096(float2* Z, const float2* tw, int tid, bool inv){
  for (int i = tid; i < 4096; i += 256){
    const int j = (int)(__brev((unsigned)i) >> 20);
    if (i < j){ float2 t = Z[i]; Z[i] = Z[j]; Z[j] = t; }
  }
  __syncthreads();
  for (int s = 1; s <= 12; ++s){
    const int half = 1 << (s - 1);
    for (int t = tid; t < 2048; t += 256){
      const int j = t & (half - 1);
      const int i0 = ((t >> (s-1)) << s) + j;
      const int i1 = i0 + half;
      float2 w = tw[j << (12 - s)];
      const float wy = inv ? -w.y : w.y;
      const float2 u = Z[i0], v = Z[i1];
      const float vr = v.x * w.x - v.y * wy;
      const float vi = v.x * wy + v.y * w.x;
      Z[i0] = make_float2(u.x + vr, u.y + vi);
      Z[i1] = make_float2(u.x - vr, u.y - vi);
    }
    __syncthreads();
  }
}

// ---------------- FFT of (q + i*k) per (b,h,d); accumulate S[f] = sum_d qf*conj(kf) ----------------
__global__ __launch_bounds__(256) void k_fftcorr(const u16* __restrict__ Qt, const u16* __restrict__ Kt,
                                                 float* __restrict__ S){
  __shared__ float2 Z[4096];      // 32 KB
  __shared__ float2 tw[2048];     // 16 KB
  const int tid = threadIdx.x;
  const int bh = blockIdx.x, dg = blockIdx.y;
  for (int k = tid; k < 2048; k += 256){
    float sn, cs;
    sincosf(-1.5339807878856412e-03f * (float)k, &sn, &cs);   // -2*pi/4096 * k
    tw[k] = make_float2(cs, sn);
  }
  float2 sa[16];
  #pragma unroll
  for (int j = 0; j < 16; ++j) sa[j] = make_float2(0.f, 0.f);
  __syncthreads();
  for (int dd = 0; dd < 16; ++dd){
    const int d = dg*16 + dd;
    const u16* q  = Qt + ((size_t)bh*64 + d) * 4096;
    const u16* kp = Kt + ((size_t)bh*64 + d) * 4096;
    for (int i = tid; i < 4096; i += 256)
      Z[i] = make_float2(bf2f(q[i]), bf2f(kp[i]));
    __syncthreads();
    fft4096(Z, tw, tid, false);
    #pragma unroll
    for (int j = 0; j < 16; ++j){
      const int f = j*256 + tid;
      const float2 a = Z[f];
      const float2 c = Z[(4096 - f) & 4095];
      const float qr = 0.5f * (a.x + c.x);
      const float qi = 0.5f * (a.y - c.y);
      const float kr = 0.5f * (a.y + c.y);
      const float ki = 0.5f * (c.x - a.x);
      sa[j].x += qr*kr + qi*ki;     // Re(qf * conj(kf))
      sa[j].y += qi*kr - qr*ki;     // Im(qf * conj(kf))
    }
    __syncthreads();
  }
  float* Sg = S + (size_t)bh * 8192;
  #pragma unroll
  for (int j = 0; j < 16; ++j){
    const int f = j*256 + tid;
    atomicAdd(&Sg[2*f + 0], sa[j].x);
    atomicAdd(&Sg[2*f + 1], sa[j].y);
  }
}

// ---------------- inverse FFT of S -> corr; softmax over L -> attn ----------------
__global__ __launch_bounds__(256) void k_isoftmax(const float* __restrict__ S, float* __restrict__ attn){
  __shared__ float2 Z[4096];
  __shared__ float2 tw[2048];
  __shared__ float red[4];
  __shared__ float bc;
  const int tid = threadIdx.x;
  const int bh = blockIdx.x;
  for (int k = tid; k < 2048; k += 256){
    float sn, cs;
    sincosf(-1.5339807878856412e-03f * (float)k, &sn, &cs);
    tw[k] = make_float2(cs, sn);
  }
  const float2* Sg = (const float2*)(S + (size_t)bh * 8192);
  for (int i = tid; i < 4096; i += 256) Z[i] = Sg[i];
  __syncthreads();
  fft4096(Z, tw, tid, true);          // unnormalized inverse
  const float scale = 1.0f / (4096.0f * 64.0f);   // 1/N (ifft) * 1/HD (mean over d)
  float cr[16];
  float lmax = -1e30f;
  #pragma unroll
  for (int j = 0; j < 16; ++j){
    const float c = Z[j*256 + tid].x * scale;
    cr[j] = c;
    lmax = fmaxf(lmax, c);
  }
  #pragma unroll
  for (int o = 32; o > 0; o >>= 1) lmax = fmaxf(lmax, __shfl_down(lmax, o));
  if ((tid & 63) == 0) red[tid >> 6] = lmax;
  __syncthreads();
  if (tid == 0) bc = fmaxf(fmaxf(red[0], red[1]), fmaxf(red[2], red[3]));
  __syncthreads();
  const float gmax = bc;
  float lsum = 0.f;
  #pragma unroll
  for (int j = 0; j < 16; ++j){ cr[j] = __expf(cr[j] - gmax); lsum += cr[j]; }
  #pragma unroll
  for (int o = 32; o > 0; o >>= 1) lsum += __shfl_down(lsum, o);
  if ((tid & 63) == 0) red[tid >> 6] = lsum;
  __syncthreads();
  if (tid == 0) bc = red[0] + red[1] + red[2] + red[3];
  __syncthreads();
  const float inv = 1.0f / bc;
  float* at = attn + (size_t)bh * 4096;
  #pragma unroll
  for (int j = 0; j < 16; ++j) at[j*256 + tid] = cr[j] * inv;
}

// ---------------- out[b,h,d] = sum_l attn[b,h,l] * V[b,l,h,d]; store lossy-transposed ----------------
__global__ __launch_bounds__(256) void k_av(const float* __restrict__ attn, const u16* __restrict__ V,
                                            float* __restrict__ oav, int ld){
  const int bh = blockIdx.x;
  const int b = bh >> 4, h = bh & 15;
  const int tid = threadIdx.x;
  const int d = tid & 63, lg = tid >> 6;
  const u16* vb = V + (size_t)b*4096*ld + h*64 + d;
  const float* at = attn + (size_t)bh * 4096;
  float acc = 0.f;
  for (int l = lg*1024; l < lg*1024 + 1024; ++l)
    acc += at[l] * bf2f(vb[(size_t)l * ld]);
  __shared__ float part[4][64];
  part[lg][d] = acc;
  __syncthreads();
  if (lg == 0)
    oav[(size_t)b*1024 + d*16 + h] = part[0][d] + part[1][d] + part[2][d] + part[3][d];  // flat idx = hd*H + h
}

// ---------------- proj = oav @ Wo^T + bo  (8 x 1024) ----------------
__global__ __launch_bounds__(256) void k_proj(const float* __restrict__ oav, const float* __restrict__ Wo,
                                              const float* __restrict__ bo, float* __restrict__ proj){
  const int b = blockIdx.x;
  const int o = blockIdx.y * 256 + threadIdx.x;
  __shared__ float xin[1024];
  for (int i = threadIdx.x; i < 1024; i += 256) xin[i] = oav[(size_t)b*1024 + i];
  __syncthreads();
  float acc = bo[o];
  const float4* wr = (const float4*)(Wo + (size_t)o * 1024);
  #pragma unroll 4
  for (int i = 0; i < 256; ++i){
    const float4 w4 = wr[i];
    acc += xin[4*i]*w4.x + xin[4*i+1]*w4.y + xin[4*i+2]*w4.z + xin[4*i+3]*w4.w;
  }
  proj[(size_t)b*1024 + o] = acc;
}

// ---------------- x1 = x + proj; x2 = x1 - movavg25(x1, zero-padded); write x2 to out ----------------
__global__ __launch_bounds__(256) void k_decomp(const float* __restrict__ x, const float* __restrict__ proj,
                                                float* __restrict__ out){
  const int row = blockIdx.x;           // b*4096 + l
  const int b = row >> 12, l = row & 4095;
  const int d = blockIdx.y * 256 + threadIdx.x;
  const float pv = proj[(size_t)b*1024 + d];
  const float* xb = x + (size_t)b * 4096 * 1024 + d;
  float wsum = 0.f; float cnt;
  if (l >= 12 && l < 4084){
    #pragma unroll
    for (int j = -12; j <= 12; ++j) wsum += xb[(size_t)(l + j) * 1024];
    cnt = 25.f;
  } else {
    cnt = 0.f;
    #pragma unroll
    for (int j = -12; j <= 12; ++j){
      const int ll = l + j;
      if (0 <= ll && ll < 4096){ wsum += xb[(size_t)ll * 1024]; cnt += 1.f; }
    }
  }
  const float xc = xb[(size_t)l * 1024];
  out[(size_t)row * 1024 + d] = xc + pv - (wsum + cnt * pv) * 0.04f;
}

extern "C" void kernel_launch(void* const* d_in, const int* in_sizes, int n_in,
                              void* d_out, int out_size, void* d_ws, size_t ws_size,
                              hipStream_t stream){
  const float* x    = (const float*)d_in[0];
  const float* ln1w = (const float*)d_in[1];
  const float* ln1b = (const float*)d_in[2];
  const float* Wq   = (const float*)d_in[3];
  const float* bq   = (const float*)d_in[4];
  const float* Wk   = (const float*)d_in[5];
  const float* bk   = (const float*)d_in[6];
  const float* Wv   = (const float*)d_in[7];
  const float* bv   = (const float*)d_in[8];
  const float* Wo   = (const float*)d_in[9];
  const float* bo   = (const float*)d_in[10];
  const float* ln2w = (const float*)d_in[11];
  const float* ln2b = (const float*)d_in[12];
  const float* W1   = (const float*)d_in[13];
  const float* b1   = (const float*)d_in[14];
  const float* W2   = (const float*)d_in[15];
  const float* b2   = (const float*)d_in[16];
  float* out = (float*)d_out;

  char* ws = (char*)d_ws;
  // Region A [0, 256MB): QKV (192MB) + Qt (64MB) early; H1 (32768x4096 bf16, 256MB) late.
  u16* QKV  = (u16*)(ws + 0);                 // (32768, 3072) bf16: cols 0-1023 Q, 1024-2047 K, 2048-3071 V
  u16* Qt   = (u16*)(ws + 201326592);
  u16* H1   = (u16*)(ws + 0);
  // Slot B [256MB, 320MB): Y(ln1) -> Kt -> Y2(ln2), 64MB each, strictly sequential lifetimes.
  u16* Y    = (u16*)(ws + 268435456);
  u16* Kt   = (u16*)(ws + 268435456);
  float* S    = (float*)(ws + 335544320);     // B*H*4096 complex f32 = 4 MB
  float* attn = (float*)(ws + 339738624);     // 2 MB
  float* oav  = (float*)(ws + 341835776);     // 32 KB
  float* proj = (float*)(ws + 341868544);     // 32 KB
  float* bqkv = (float*)(ws + 341901312);     // 12 KB (pad to 16K)
  u16* Wqkvb  = (u16*)(ws + 341917696);       // 6 MB
  u16* W1b    = (u16*)(ws + 348209152);       // 8 MB
  u16* W2b    = (u16*)(ws + 356597760);       // 8 MB -> ends ~348 MB

  // weights -> bf16 (Wq/Wk/Wv concatenated row-wise into one (3072,1024) matrix)
  k_cvt<<<4096, 256, 0, stream>>>(Wq, Wqkvb,           1048576);
  k_cvt<<<4096, 256, 0, stream>>>(Wk, Wqkvb + 1048576, 1048576);
  k_cvt<<<4096, 256, 0, stream>>>(Wv, Wqkvb + 2097152, 1048576);
  k_cvt<<<16384, 256, 0, stream>>>(W1, W1b, 4194304);
  k_cvt<<<16384, 256, 0, stream>>>(W2, W2b, 4194304);
  k_cat3<<<4, 256, 0, stream>>>(bq, bk, bv, bqkv);

  // y = LN1(x)
  k_ln<<<32768, 256, 0, stream>>>(x, ln1w, ln1b, Y);

  // fused QKV projection: (32768 x 3072) = Y @ Wqkv^T + bqkv
  k_gemm2<0><<<dim3(12, 128), 512, 0, stream>>>(Y, Wqkvb, bqkv, QKV, 32768, 3072, 1024);

  // transpose to (B,H,64,L) for contiguous FFT columns
  k_tr<<<dim3(64, 128), 256, 0, stream>>>(QKV,        Qt, 3072);
  k_tr<<<dim3(64, 128), 256, 0, stream>>>(QKV + 1024, Kt, 3072);

  // S[f] = sum_d rfft(Q_d) * conj(rfft(K_d))   (full Hermitian spectrum)
  hipMemsetAsync(S, 0, 4194304, stream);
  k_fftcorr<<<dim3(128, 4), 256, 0, stream>>>(Qt, Kt, S);
  // corr = ifft(S)/(N*HD); attn = softmax(corr)
  k_isoftmax<<<128, 256, 0, stream>>>(S, attn);
  // out_av[b, hd*16+h] = sum_l attn * V
  k_av<<<128, 256, 0, stream>>>(attn, QKV + 2048, oav, 3072);
  // proj = oav @ Wo^T + bo
  k_proj<<<dim3(8, 4), 256, 0, stream>>>(oav, Wo, bo, proj);

  // x2 = (x + proj) - movavg25(x + proj)  -> d_out
  k_decomp<<<dim3(32768, 4), 256, 0, stream>>>(x, proj, out);

  // y2 = LN2(x2)
  k_ln<<<32768, 256, 0, stream>>>(out, ln2w, ln2b, Y);

  // MLP: h1 = gelu(y2 @ W1^T + b1);  d_out = x2 + h1 @ W2^T + b2
  k_gemm2<1><<<dim3(16, 128), 512, 0, stream>>>(Y, W1b, b1, H1, 32768, 4096, 1024);
  k_gemm2<2><<<dim3(4, 128), 512, 0, stream>>>(H1, W2b, b2, out, 32768, 1024, 4096);
}

// Round 3
// 1903.794 us; speedup vs baseline: 1.0446x; 1.0446x over previous
//
#include <hip/hip_runtime.h>

#define DEV __device__ __forceinline__

typedef __attribute__((ext_vector_type(8))) short bf16x8;
typedef __attribute__((ext_vector_type(4))) float f32x4;
typedef unsigned short u16;
typedef __attribute__((address_space(1))) const void* gvp;
typedef __attribute__((address_space(3))) void* svp;

DEV u16 f2bf(float f){
  unsigned u = __float_as_uint(f);
  u = (u + 0x7FFFu + ((u >> 16) & 1u)) >> 16;
  return (u16)u;
}
DEV float bf2f(u16 v){ return __uint_as_float(((unsigned)v) << 16); }

// ---------------- convert f32 -> bf16 ----------------
__global__ void k_cvt(const float* __restrict__ s, u16* __restrict__ d, int n){
  int i = blockIdx.x * 256 + threadIdx.x;
  if (i < n) d[i] = f2bf(s[i]);
}

// ---------------- concat 3 bias vectors (1024 each) ----------------
__global__ void k_cat3(const float* __restrict__ a, const float* __restrict__ b,
                       const float* __restrict__ c, float* __restrict__ o){
  int i = blockIdx.x * 256 + threadIdx.x;
  if (i < 1024){ o[i] = a[i]; o[1024 + i] = b[i]; o[2048 + i] = c[i]; }
}

// ---------------- layernorm over D=1024, bf16 out ----------------
__global__ __launch_bounds__(256) void k_ln(const float* __restrict__ x, const float* __restrict__ w,
                                            const float* __restrict__ b, u16* __restrict__ y){
  const int row = blockIdx.x;
  const int tid = threadIdx.x;
  const float4 v = ((const float4*)(x + (size_t)row * 1024))[tid];
  float s1 = v.x + v.y + v.z + v.w;
  float s2 = v.x*v.x + v.y*v.y + v.z*v.z + v.w*v.w;
  #pragma unroll
  for (int o = 32; o > 0; o >>= 1){ s1 += __shfl_down(s1, o); s2 += __shfl_down(s2, o); }
  __shared__ float r1[4], r2[4];
  __shared__ float mu_s, rs_s;
  const int wv = tid >> 6;
  if ((tid & 63) == 0){ r1[wv] = s1; r2[wv] = s2; }
  __syncthreads();
  if (tid == 0){
    float t1 = r1[0]+r1[1]+r1[2]+r1[3], t2 = r2[0]+r2[1]+r2[2]+r2[3];
    float mu = t1 * (1.0f/1024.0f);
    float var = t2 * (1.0f/1024.0f) - mu*mu;
    mu_s = mu; rs_s = rsqrtf(var + 1e-6f);
  }
  __syncthreads();
  const float mu = mu_s, rs = rs_s;
  const float4 wv4 = ((const float4*)w)[tid];
  const float4 bv4 = ((const float4*)b)[tid];
  ushort4 o4;
  o4.x = f2bf((v.x-mu)*rs*wv4.x + bv4.x);
  o4.y = f2bf((v.y-mu)*rs*wv4.y + bv4.y);
  o4.z = f2bf((v.z-mu)*rs*wv4.z + bv4.z);
  o4.w = f2bf((v.w-mu)*rs*wv4.w + bv4.w);
  ((ushort4*)(y + (size_t)row*1024))[tid] = o4;
}

// ---------------- 256x256 tile, BK=64, 2-phase double-buffered bf16 MFMA GEMM ----------------
// C = A(MxK) * Bw(NxK)^T + bias.  1D grid with XCD-bijective bm-major swizzle.
// MODE 0: bf16 store. MODE 1: gelu then bf16 store. MODE 2: f32 out[off] += v
template<int MODE>
__launch_bounds__(512, 2)
__global__ void k_gemm3(const u16* __restrict__ A, const u16* __restrict__ Bw,
                        const float* __restrict__ bias, void* __restrict__ out,
                        int M, int N, int K)
{
  __shared__ __align__(16) u16 LA[2][16384];   // 2 x (256 rows x 64 k) bf16 = 64KB
  __shared__ __align__(16) u16 LB[2][16384];   // 64KB
  const int tid = threadIdx.x;
  const int wave = tid >> 6, lane = tid & 63;
  const int l15 = lane & 15, l4 = lane >> 4;
  const int wr = wave >> 2, wc = wave & 3;     // 2M x 4N wave grid; per-wave out 128x64
  (void)M;

  // XCD-bijective swizzle (grid % 8 == 0 for all our shapes), bm-major (bn inner)
  const int nwg = gridDim.x;
  const int q8 = nwg >> 3;
  const int wg = (blockIdx.x & 7) * q8 + (blockIdx.x >> 3);
  const int NBN = N >> 8;
  const int bm = wg / NBN, bn = wg % NBN;
  const int NT = K >> 6;                       // K-tiles of 64

  // ---- staging geometry: linear LDS dest; inverse-swizzled global source ----
  // wave w, instr i covers LDS rows w*32+i*8 .. +7 (128B each, contiguous 1KB).
  // lane -> row = +lane>>3, 16B-chunk-in-row = lane&7; stored global chunk = (lane&7)^(row&7).
  const int srow = wave*32 + (lane >> 3);
  const int sch8 = ((lane & 7) ^ ((lane >> 3) & 7)) * 8;   // u16 units
  const u16* gA = A  + ((size_t)bm*256 + srow) * K + sch8;
  const u16* gB = Bw + ((size_t)bn*256 + srow) * K + sch8;
  const int ldsb = wave * 2048;                // u16; + i*512 per instr

  // ---- swizzled ds_read offsets (u16): frag(row r, chunk c) at r*64 + (c^(r&7))*8 ----
  // kk=0: c = l4 (0..3); kk=32: c = l4|4  -> addr(kk=32) = addr(kk=0) ^ 32
  const int swz = (l4 ^ (l15 & 7)) * 8;
  const int arow = (wr*128 + l15) * 64;        // + m*1024 per m-frag
  const int brow = (wc*64  + l15) * 64;        // + n*1024 per n-frag

  f32x4 acc[8][4];
  const f32x4 z4 = {0.f, 0.f, 0.f, 0.f};
  #pragma unroll
  for (int m = 0; m < 8; ++m)
    #pragma unroll
    for (int n = 0; n < 4; ++n) acc[m][n] = z4;

#define STAGE(bi, tki) do{ \
    const u16* a_ = gA + (size_t)(tki) * 64; \
    const u16* b_ = gB + (size_t)(tki) * 64; \
    u16* la_ = &LA[bi][ldsb]; \
    u16* lb_ = &LB[bi][ldsb]; \
    _Pragma("unroll") \
    for (int i_ = 0; i_ < 4; ++i_){ \
      __builtin_amdgcn_global_load_lds((gvp)(a_ + (size_t)i_*8*K), (svp)(la_ + i_*512), 16, 0, 0); \
      __builtin_amdgcn_global_load_lds((gvp)(b_ + (size_t)i_*8*K), (svp)(lb_ + i_*512), 16, 0, 0); \
    } \
  }while(0)

  // prologue
  STAGE(0, 0);
  asm volatile("s_waitcnt vmcnt(0)" ::: "memory");
  __builtin_amdgcn_s_barrier();

  int cur = 0;
  for (int t = 0; t < NT; ++t){
    if (t + 1 < NT) STAGE(cur ^ 1, t + 1);     // issue next-tile loads FIRST
    const u16* bA = &LA[cur][0];
    const u16* bB = &LB[cur][0];
    #pragma unroll
    for (int kk = 0; kk < 2; ++kk){
      const int kx = kk ? 32 : 0;
      bf16x8 fb[4], fa[8];
      #pragma unroll
      for (int n = 0; n < 4; ++n) fb[n] = *(const bf16x8*)(bB + brow + n*1024 + (swz ^ kx));
      #pragma unroll
      for (int m = 0; m < 8; ++m) fa[m] = *(const bf16x8*)(bA + arow + m*1024 + (swz ^ kx));
      #pragma unroll
      for (int m = 0; m < 8; ++m)
        #pragma unroll
        for (int n = 0; n < 4; ++n)
          acc[m][n] = __builtin_amdgcn_mfma_f32_16x16x32_bf16(fa[m], fb[n], acc[m][n], 0, 0, 0);
    }
    if (t + 1 < NT){
      asm volatile("s_waitcnt vmcnt(0)" ::: "memory");
      __builtin_amdgcn_s_barrier();
      cur ^= 1;
    }
  }
#undef STAGE

  #pragma unroll
  for (int m = 0; m < 8; ++m){
    const int gr0 = bm*256 + wr*128 + m*16 + l4*4;
    #pragma unroll
    for (int n = 0; n < 4; ++n){
      const int gc = bn*256 + wc*64 + n*16 + l15;
      const float bv = bias[gc];
      #pragma unroll
      for (int r2 = 0; r2 < 4; ++r2){
        const size_t off = (size_t)(gr0 + r2) * N + gc;
        float v = acc[m][n][r2] + bv;
        if (MODE == 0){
          ((u16*)out)[off] = f2bf(v);
        } else if (MODE == 1){
          const float a = 0.7978845608028654f * (v + 0.044715f * v * v * v);
          const float e = __expf(2.0f * a);
          const float th = (e - 1.0f) / (e + 1.0f);
          ((u16*)out)[off] = f2bf(0.5f * v * (1.0f + th));
        } else {
          float* op = (float*)out;
          op[off] += v;
        }
      }
    }
  }
}

// ---------------- transpose (B,L,ld) slice -> (B,H,64,L) per (b,h), bf16 ----------------
__global__ __launch_bounds__(256) void k_tr(const u16* __restrict__ Q, u16* __restrict__ Qt, int ld){
  __shared__ u16 Ls[64][65];
  const int tid = threadIdx.x;
  const int bh = blockIdx.y;
  const int b = bh >> 4, h = bh & 15;
  const int l0 = blockIdx.x * 64;
  #pragma unroll
  for (int i = 0; i < 16; ++i){
    const int id = i*256 + tid;
    const int lr = id >> 6, dc = id & 63;
    Ls[lr][dc] = Q[((size_t)b*4096 + l0 + lr)*ld + h*64 + dc];
  }
  __syncthreads();
  #pragma unroll
  for (int i = 0; i < 16; ++i){
    const int id = i*256 + tid;
    const int dr = id >> 6, lc = id & 63;
    Qt[((size_t)bh*64 + dr)*4096 + l0 + lc] = Ls[lc][dr];
  }
}

// ---------------- in-LDS radix-2 DIT FFT, N=4096, 256 threads ----------------
DEV void fft4096(float2* Z, const float2* tw, int tid, bool inv){
  for (int i = tid; i < 4096; i += 256){
    const int j = (int)(__brev((unsigned)i) >> 20);
    if (i < j){ float2 t = Z[i]; Z[i] = Z[j]; Z[j] = t; }
  }
  __syncthreads();
  for (int s = 1; s <= 12; ++s){
    const int half = 1 << (s - 1);
    for (int t = tid; t < 2048; t += 256){
      const int j = t & (half - 1);
      const int i0 = ((t >> (s-1)) << s) + j;
      const int i1 = i0 + half;
      float2 w = tw[j << (12 - s)];
      const float wy = inv ? -w.y : w.y;
      const float2 u = Z[i0], v = Z[i1];
      const float vr = v.x * w.x - v.y * wy;
      const float vi = v.x * wy + v.y * w.x;
      Z[i0] = make_float2(u.x + vr, u.y + vi);
      Z[i1] = make_float2(u.x - vr, u.y - vi);
    }
    __syncthreads();
  }
}

// ---------------- FFT of (q + i*k) per (b,h,d); accumulate S[f] = sum_d qf*conj(kf) ----------------
__global__ __launch_bounds__(256) void k_fftcorr(const u16* __restrict__ Qt, const u16* __restrict__ Kt,
                                                 float* __restrict__ S){
  __shared__ float2 Z[4096];      // 32 KB
  __shared__ float2 tw[2048];     // 16 KB
  const int tid = threadIdx.x;
  const int bh = blockIdx.x, dg = blockIdx.y;
  for (int k = tid; k < 2048; k += 256){
    float sn, cs;
    sincosf(-1.5339807878856412e-03f * (float)k, &sn, &cs);   // -2*pi/4096 * k
    tw[k] = make_float2(cs, sn);
  }
  float2 sa[16];
  #pragma unroll
  for (int j = 0; j < 16; ++j) sa[j] = make_float2(0.f, 0.f);
  __syncthreads();
  for (int dd = 0; dd < 16; ++dd){
    const int d = dg*16 + dd;
    const u16* q  = Qt + ((size_t)bh*64 + d) * 4096;
    const u16* kp = Kt + ((size_t)bh*64 + d) * 4096;
    for (int i = tid; i < 4096; i += 256)
      Z[i] = make_float2(bf2f(q[i]), bf2f(kp[i]));
    __syncthreads();
    fft4096(Z, tw, tid, false);
    #pragma unroll
    for (int j = 0; j < 16; ++j){
      const int f = j*256 + tid;
      const float2 a = Z[f];
      const float2 c = Z[(4096 - f) & 4095];
      const float qr = 0.5f * (a.x + c.x);
      const float qi = 0.5f * (a.y - c.y);
      const float kr = 0.5f * (a.y + c.y);
      const float ki = 0.5f * (c.x - a.x);
      sa[j].x += qr*kr + qi*ki;     // Re(qf * conj(kf))
      sa[j].y += qi*kr - qr*ki;     // Im(qf * conj(kf))
    }
    __syncthreads();
  }
  float* Sg = S + (size_t)bh * 8192;
  #pragma unroll
  for (int j = 0; j < 16; ++j){
    const int f = j*256 + tid;
    atomicAdd(&Sg[2*f + 0], sa[j].x);
    atomicAdd(&Sg[2*f + 1], sa[j].y);
  }
}

// ---------------- inverse FFT of S -> corr; softmax over L -> attn ----------------
__global__ __launch_bounds__(256) void k_isoftmax(const float* __restrict__ S, float* __restrict__ attn){
  __shared__ float2 Z[4096];
  __shared__ float2 tw[2048];
  __shared__ float red[4];
  __shared__ float bc;
  const int tid = threadIdx.x;
  const int bh = blockIdx.x;
  for (int k = tid; k < 2048; k += 256){
    float sn, cs;
    sincosf(-1.5339807878856412e-03f * (float)k, &sn, &cs);
    tw[k] = make_float2(cs, sn);
  }
  const float2* Sg = (const float2*)(S + (size_t)bh * 8192);
  for (int i = tid; i < 4096; i += 256) Z[i] = Sg[i];
  __syncthreads();
  fft4096(Z, tw, tid, true);          // unnormalized inverse
  const float scale = 1.0f / (4096.0f * 64.0f);   // 1/N (ifft) * 1/HD (mean over d)
  float cr[16];
  float lmax = -1e30f;
  #pragma unroll
  for (int j = 0; j < 16; ++j){
    const float c = Z[j*256 + tid].x * scale;
    cr[j] = c;
    lmax = fmaxf(lmax, c);
  }
  #pragma unroll
  for (int o = 32; o > 0; o >>= 1) lmax = fmaxf(lmax, __shfl_down(lmax, o));
  if ((tid & 63) == 0) red[tid >> 6] = lmax;
  __syncthreads();
  if (tid == 0) bc = fmaxf(fmaxf(red[0], red[1]), fmaxf(red[2], red[3]));
  __syncthreads();
  const float gmax = bc;
  float lsum = 0.f;
  #pragma unroll
  for (int j = 0; j < 16; ++j){ cr[j] = __expf(cr[j] - gmax); lsum += cr[j]; }
  #pragma unroll
  for (int o = 32; o > 0; o >>= 1) lsum += __shfl_down(lsum, o);
  if ((tid & 63) == 0) red[tid >> 6] = lsum;
  __syncthreads();
  if (tid == 0) bc = red[0] + red[1] + red[2] + red[3];
  __syncthreads();
  const float inv = 1.0f / bc;
  float* at = attn + (size_t)bh * 4096;
  #pragma unroll
  for (int j = 0; j < 16; ++j) at[j*256 + tid] = cr[j] * inv;
}

// ---------------- out[b,h,d] = sum_l attn[b,h,l] * V[b,l,h,d]; store lossy-transposed ----------------
__global__ __launch_bounds__(256) void k_av(const float* __restrict__ attn, const u16* __restrict__ V,
                                            float* __restrict__ oav, int ld){
  const int bh = blockIdx.x;
  const int b = bh >> 4, h = bh & 15;
  const int tid = threadIdx.x;
  const int d = tid & 63, lg = tid >> 6;
  const u16* vb = V + (size_t)b*4096*ld + h*64 + d;
  const float* at = attn + (size_t)bh * 4096;
  float acc = 0.f;
  for (int l = lg*1024; l < lg*1024 + 1024; ++l)
    acc += at[l] * bf2f(vb[(size_t)l * ld]);
  __shared__ float part[4][64];
  part[lg][d] = acc;
  __syncthreads();
  if (lg == 0)
    oav[(size_t)b*1024 + d*16 + h] = part[0][d] + part[1][d] + part[2][d] + part[3][d];  // flat idx = hd*H + h
}

// ---------------- proj = oav @ Wo^T + bo  (8 x 1024) ----------------
__global__ __launch_bounds__(256) void k_proj(const float* __restrict__ oav, const float* __restrict__ Wo,
                                              const float* __restrict__ bo, float* __restrict__ proj){
  const int b = blockIdx.x;
  const int o = blockIdx.y * 256 + threadIdx.x;
  __shared__ float xin[1024];
  for (int i = threadIdx.x; i < 1024; i += 256) xin[i] = oav[(size_t)b*1024 + i];
  __syncthreads();
  float acc = bo[o];
  const float4* wr = (const float4*)(Wo + (size_t)o * 1024);
  #pragma unroll 4
  for (int i = 0; i < 256; ++i){
    const float4 w4 = wr[i];
    acc += xin[4*i]*w4.x + xin[4*i+1]*w4.y + xin[4*i+2]*w4.z + xin[4*i+3]*w4.w;
  }
  proj[(size_t)b*1024 + o] = acc;
}

// ---------------- x1 = x + proj; x2 = x1 - movavg25(x1, zero-padded); write x2 to out ----------------
__global__ __launch_bounds__(256) void k_decomp(const float* __restrict__ x, const float* __restrict__ proj,
                                                float* __restrict__ out){
  const int row = blockIdx.x;           // b*4096 + l
  const int b = row >> 12, l = row & 4095;
  const int d = blockIdx.y * 256 + threadIdx.x;
  const float pv = proj[(size_t)b*1024 + d];
  const float* xb = x + (size_t)b * 4096 * 1024 + d;
  float wsum = 0.f; float cnt;
  if (l >= 12 && l < 4084){
    #pragma unroll
    for (int j = -12; j <= 12; ++j) wsum += xb[(size_t)(l + j) * 1024];
    cnt = 25.f;
  } else {
    cnt = 0.f;
    #pragma unroll
    for (int j = -12; j <= 12; ++j){
      const int ll = l + j;
      if (0 <= ll && ll < 4096){ wsum += xb[(size_t)ll * 1024]; cnt += 1.f; }
    }
  }
  const float xc = xb[(size_t)l * 1024];
  out[(size_t)row * 1024 + d] = xc + pv - (wsum + cnt * pv) * 0.04f;
}

extern "C" void kernel_launch(void* const* d_in, const int* in_sizes, int n_in,
                              void* d_out, int out_size, void* d_ws, size_t ws_size,
                              hipStream_t stream){
  const float* x    = (const float*)d_in[0];
  const float* ln1w = (const float*)d_in[1];
  const float* ln1b = (const float*)d_in[2];
  const float* Wq   = (const float*)d_in[3];
  const float* bq   = (const float*)d_in[4];
  const float* Wk   = (const float*)d_in[5];
  const float* bk   = (const float*)d_in[6];
  const float* Wv   = (const float*)d_in[7];
  const float* bv   = (const float*)d_in[8];
  const float* Wo   = (const float*)d_in[9];
  const float* bo   = (const float*)d_in[10];
  const float* ln2w = (const float*)d_in[11];
  const float* ln2b = (const float*)d_in[12];
  const float* W1   = (const float*)d_in[13];
  const float* b1   = (const float*)d_in[14];
  const float* W2   = (const float*)d_in[15];
  const float* b2   = (const float*)d_in[16];
  float* out = (float*)d_out;

  char* ws = (char*)d_ws;
  // Region A [0, 256MB): QKV (192MB) + Qt (64MB) early; H1 (32768x4096 bf16, 256MB) late.
  u16* QKV  = (u16*)(ws + 0);                 // (32768, 3072) bf16: cols 0-1023 Q, 1024-2047 K, 2048-3071 V
  u16* Qt   = (u16*)(ws + 201326592);
  u16* H1   = (u16*)(ws + 0);
  // Slot B [256MB, 320MB): Y(ln1) -> Kt -> Y2(ln2), 64MB each, strictly sequential lifetimes.
  u16* Y    = (u16*)(ws + 268435456);
  u16* Kt   = (u16*)(ws + 268435456);
  float* S    = (float*)(ws + 335544320);     // B*H*4096 complex f32 = 4 MB
  float* attn = (float*)(ws + 339738624);     // 2 MB
  float* oav  = (float*)(ws + 341835776);     // 32 KB
  float* proj = (float*)(ws + 341868544);     // 32 KB
  float* bqkv = (float*)(ws + 341901312);     // 12 KB (pad to 16K)
  u16* Wqkvb  = (u16*)(ws + 341917696);       // 6 MB
  u16* W1b    = (u16*)(ws + 348209152);       // 8 MB
  u16* W2b    = (u16*)(ws + 356597760);       // 8 MB -> ends ~348 MB

  // weights -> bf16 (Wq/Wk/Wv concatenated row-wise into one (3072,1024) matrix)
  k_cvt<<<4096, 256, 0, stream>>>(Wq, Wqkvb,           1048576);
  k_cvt<<<4096, 256, 0, stream>>>(Wk, Wqkvb + 1048576, 1048576);
  k_cvt<<<4096, 256, 0, stream>>>(Wv, Wqkvb + 2097152, 1048576);
  k_cvt<<<16384, 256, 0, stream>>>(W1, W1b, 4194304);
  k_cvt<<<16384, 256, 0, stream>>>(W2, W2b, 4194304);
  k_cat3<<<4, 256, 0, stream>>>(bq, bk, bv, bqkv);

  // y = LN1(x)
  k_ln<<<32768, 256, 0, stream>>>(x, ln1w, ln1b, Y);

  // fused QKV projection: (32768 x 3072) = Y @ Wqkv^T + bqkv  (grid = 128*12, %8==0)
  k_gemm3<0><<<1536, 512, 0, stream>>>(Y, Wqkvb, bqkv, QKV, 32768, 3072, 1024);

  // transpose to (B,H,64,L) for contiguous FFT columns
  k_tr<<<dim3(64, 128), 256, 0, stream>>>(QKV,        Qt, 3072);
  k_tr<<<dim3(64, 128), 256, 0, stream>>>(QKV + 1024, Kt, 3072);

  // S[f] = sum_d rfft(Q_d) * conj(rfft(K_d))   (full Hermitian spectrum)
  hipMemsetAsync(S, 0, 4194304, stream);
  k_fftcorr<<<dim3(128, 4), 256, 0, stream>>>(Qt, Kt, S);
  // corr = ifft(S)/(N*HD); attn = softmax(corr)
  k_isoftmax<<<128, 256, 0, stream>>>(S, attn);
  // out_av[b, hd*16+h] = sum_l attn * V
  k_av<<<128, 256, 0, stream>>>(attn, QKV + 2048, oav, 3072);
  // proj = oav @ Wo^T + bo
  k_proj<<<dim3(8, 4), 256, 0, stream>>>(oav, Wo, bo, proj);

  // x2 = (x + proj) - movavg25(x + proj)  -> d_out
  k_decomp<<<dim3(32768, 4), 256, 0, stream>>>(x, proj, out);

  // y2 = LN2(x2)
  k_ln<<<32768, 256, 0, stream>>>(out, ln2w, ln2b, Y);

  // MLP: h1 = gelu(y2 @ W1^T + b1);  d_out = x2 + h1 @ W2^T + b2
  k_gemm3<1><<<2048, 512, 0, stream>>>(Y, W1b, b1, H1, 32768, 4096, 1024);
  k_gemm3<2><<<512, 512, 0, stream>>>(H1, W2b, b2, out, 32768, 1024, 4096);
}

// Round 4
// 1853.410 us; speedup vs baseline: 1.0730x; 1.0272x over previous
//
#include <hip/hip_runtime.h>

#define DEV __device__ __forceinline__

typedef __attribute__((ext_vector_type(8))) short bf16x8;
typedef __attribute__((ext_vector_type(4))) float f32x4;
typedef unsigned short u16;
typedef __attribute__((address_space(1))) const void* gvp;
typedef __attribute__((address_space(3))) void* svp;

DEV u16 f2bf(float f){
  unsigned u = __float_as_uint(f);
  u = (u + 0x7FFFu + ((u >> 16) & 1u)) >> 16;
  return (u16)u;
}
DEV float bf2f(u16 v){ return __uint_as_float(((unsigned)v) << 16); }

// ---------------- convert f32 -> bf16 ----------------
__global__ void k_cvt(const float* __restrict__ s, u16* __restrict__ d, int n){
  int i = blockIdx.x * 256 + threadIdx.x;
  if (i < n) d[i] = f2bf(s[i]);
}

// ---------------- concat 3 bias vectors (1024 each) ----------------
__global__ void k_cat3(const float* __restrict__ a, const float* __restrict__ b,
                       const float* __restrict__ c, float* __restrict__ o){
  int i = blockIdx.x * 256 + threadIdx.x;
  if (i < 1024){ o[i] = a[i]; o[1024 + i] = b[i]; o[2048 + i] = c[i]; }
}

// ---------------- layernorm over D=1024, bf16 out ----------------
__global__ __launch_bounds__(256) void k_ln(const float* __restrict__ x, const float* __restrict__ w,
                                            const float* __restrict__ b, u16* __restrict__ y){
  const int row = blockIdx.x;
  const int tid = threadIdx.x;
  const float4 v = ((const float4*)(x + (size_t)row * 1024))[tid];
  float s1 = v.x + v.y + v.z + v.w;
  float s2 = v.x*v.x + v.y*v.y + v.z*v.z + v.w*v.w;
  #pragma unroll
  for (int o = 32; o > 0; o >>= 1){ s1 += __shfl_down(s1, o); s2 += __shfl_down(s2, o); }
  __shared__ float r1[4], r2[4];
  __shared__ float mu_s, rs_s;
  const int wv = tid >> 6;
  if ((tid & 63) == 0){ r1[wv] = s1; r2[wv] = s2; }
  __syncthreads();
  if (tid == 0){
    float t1 = r1[0]+r1[1]+r1[2]+r1[3], t2 = r2[0]+r2[1]+r2[2]+r2[3];
    float mu = t1 * (1.0f/1024.0f);
    float var = t2 * (1.0f/1024.0f) - mu*mu;
    mu_s = mu; rs_s = rsqrtf(var + 1e-6f);
  }
  __syncthreads();
  const float mu = mu_s, rs = rs_s;
  const float4 wv4 = ((const float4*)w)[tid];
  const float4 bv4 = ((const float4*)b)[tid];
  ushort4 o4;
  o4.x = f2bf((v.x-mu)*rs*wv4.x + bv4.x);
  o4.y = f2bf((v.y-mu)*rs*wv4.y + bv4.y);
  o4.z = f2bf((v.z-mu)*rs*wv4.z + bv4.z);
  o4.w = f2bf((v.w-mu)*rs*wv4.w + bv4.w);
  ((ushort4*)(y + (size_t)row*1024))[tid] = o4;
}

// ---------------- 256x256 tile, BK=64, 8-phase counted-vmcnt bf16 MFMA GEMM ----------------
// C = A(MxK) * Bw(NxK)^T + bias.  1D grid, XCD-bijective bm-major swizzle.
// Quadrant phases per K-tile: (0,0),(0,1),(1,1),(1,0); fa held across qb-phases, fb across qa.
// Staging: P1:{A1,B0}(u+1) P3:A0(u+2) P4:B1(u+2) P5:{A1,B0}(u+2) P7:A0(u+3) P8:B1(u+3).
// vmcnt(4) only at P4 (confirms tile u+1) and P8 (confirms tile u+2).
// MODE 0: bf16 store. MODE 1: gelu then bf16 store. MODE 2: f32 out[off] += v
template<int MODE>
__launch_bounds__(512, 2)
__global__ void k_gemm4(const u16* __restrict__ A, const u16* __restrict__ Bw,
                        const float* __restrict__ bias, void* __restrict__ out,
                        int M, int N, int K)
{
  __shared__ __align__(16) u16 LA[2][16384];   // [db][256 rows x 64 k] = 2 x 32KB
  __shared__ __align__(16) u16 LB[2][16384];
  const int tid = threadIdx.x;
  const int wave = tid >> 6, lane = tid & 63;
  const int l15 = lane & 15, l4 = lane >> 4;
  const int wrq = wave >> 2, wcq = wave & 3;   // wave pos inside a 128x128 quadrant
  (void)M;

  // XCD-bijective swizzle (grid % 8 == 0 for all our shapes), bm-major (bn inner)
  const int nwg = gridDim.x;
  const int q8 = nwg >> 3;
  const int wg = (blockIdx.x & 7) * q8 + (blockIdx.x >> 3);
  const int NBN = N >> 8;
  const int bm = wg / NBN, bn = wg % NBN;
  const int NT = K >> 6, NI = NT >> 1;

  // ---- staging geometry: linear LDS dest; inverse-swizzled global source ----
  const int sr8 = lane >> 3;
  const int sch8 = ((lane & 7) ^ (sr8 & 7)) * 8;           // u16 units
  const u16* gA = A  + ((size_t)(bm*256 + wave*16 + sr8)) * K + sch8;
  const u16* gB = Bw + ((size_t)(bn*256 + wave*16 + sr8)) * K + sch8;
  const size_t gH = (size_t)128 * K;                        // +128 rows (half select)
  const size_t gJ = (size_t)8 * K;                          // +8 rows (instr j=1)
  const int lbase = wave * 1024;                            // u16; + half*8192 + j*512

  // ---- swizzled ds_read offsets (u16): frag(row r, chunk c) at r*64 + (c^(r&7))*8 ----
  const int swz = (l4 ^ (l15 & 7)) * 8;

  f32x4 acc[8][4];
  const f32x4 z4 = {0.f, 0.f, 0.f, 0.f};
  #pragma unroll
  for (int m = 0; m < 8; ++m)
    #pragma unroll
    for (int n = 0; n < 4; ++n) acc[m][n] = z4;

  const u16* pA0 = &LA[0][0]; const u16* pA1 = &LA[1][0];
  const u16* pB0 = &LB[0][0]; const u16* pB1 = &LB[1][0];

#define STG(LD, G, DB, HALF, TK) do{ \
    const int tk_ = (TK) < NT ? (TK) : NT - 1; \
    const u16* g_ = (G) + (size_t)tk_ * 64 + (size_t)(HALF) * gH; \
    u16* l_ = &LD[DB][lbase + (HALF) * 8192]; \
    __builtin_amdgcn_global_load_lds((gvp)g_,        (svp)l_,        16, 0, 0); \
    __builtin_amdgcn_global_load_lds((gvp)(g_ + gJ), (svp)(l_ + 512),16, 0, 0); \
  }while(0)

#define LDA_FA(BASE, QA) do{ \
    _Pragma("unroll") for (int mm = 0; mm < 4; ++mm){ \
      const int r_ = ((QA)*128 + wrq*64 + mm*16 + l15) * 64; \
      fa[mm*2+0] = *(const bf16x8*)((BASE) + r_ + swz); \
      fa[mm*2+1] = *(const bf16x8*)((BASE) + r_ + (swz ^ 32)); \
    } }while(0)

#define LDB_FB(BASE, QB) do{ \
    _Pragma("unroll") for (int nn = 0; nn < 2; ++nn){ \
      const int r_ = ((QB)*128 + wcq*32 + nn*16 + l15) * 64; \
      fb[nn*2+0] = *(const bf16x8*)((BASE) + r_ + swz); \
      fb[nn*2+1] = *(const bf16x8*)((BASE) + r_ + (swz ^ 32)); \
    } }while(0)

#define MFMA16(QA, QB) do{ \
    __builtin_amdgcn_s_setprio(1); \
    _Pragma("unroll") for (int kk = 0; kk < 2; ++kk) \
    _Pragma("unroll") for (int mm = 0; mm < 4; ++mm) \
    _Pragma("unroll") for (int nn = 0; nn < 2; ++nn) \
      acc[(QA)*4+mm][(QB)*2+nn] = __builtin_amdgcn_mfma_f32_16x16x32_bf16( \
          fa[mm*2+kk], fb[nn*2+kk], acc[(QA)*4+mm][(QB)*2+nn], 0, 0, 0); \
    __builtin_amdgcn_s_setprio(0); \
  }while(0)

#define SBAR asm volatile("s_barrier" ::: "memory")
#define VM4  asm volatile("s_waitcnt vmcnt(4)" ::: "memory")

  // ---- prologue: tile0 (all 4 regions) + A0(1) + B1(1); confirm tile0 ----
  STG(LA, gA, 0, 0, 0); STG(LA, gA, 0, 1, 0);
  STG(LB, gB, 0, 0, 0); STG(LB, gB, 0, 1, 0);
  STG(LA, gA, 1, 0, 1);
  STG(LB, gB, 1, 1, 1);
  VM4; SBAR;

  for (int it = 0; it < NI; ++it){
    const int u = 2 * it;
    bf16x8 fa[8], fb[4];
    // ---- tile u in db0 ----
    // P1: quadrant (0,0); stage A1,B0 of u+1 -> db1
    LDA_FA(pA0, 0); LDB_FB(pB0, 0);
    STG(LA, gA, 1, 1, u+1); STG(LB, gB, 1, 0, u+1);
    SBAR; MFMA16(0, 0); SBAR;
    // P2: (0,1)
    LDB_FB(pB0, 1);
    SBAR; MFMA16(0, 1); SBAR;
    // P3: (1,1); stage A0 of u+2 -> db0
    LDA_FA(pA0, 1);
    STG(LA, gA, 0, 0, u+2);
    SBAR; MFMA16(1, 1); SBAR;
    // P4: (1,0); stage B1 of u+2 -> db0; confirm tile u+1
    LDB_FB(pB0, 0);
    STG(LB, gB, 0, 1, u+2);
    VM4; SBAR; MFMA16(1, 0); SBAR;
    // ---- tile u+1 in db1 ----
    // P5: (0,0); stage A1,B0 of u+2 -> db0
    LDA_FA(pA1, 0); LDB_FB(pB1, 0);
    STG(LA, gA, 0, 1, u+2); STG(LB, gB, 0, 0, u+2);
    SBAR; MFMA16(0, 0); SBAR;
    // P6: (0,1)
    LDB_FB(pB1, 1);
    SBAR; MFMA16(0, 1); SBAR;
    // P7: (1,1); stage A0 of u+3 -> db1
    LDA_FA(pA1, 1);
    STG(LA, gA, 1, 0, u+3);
    SBAR; MFMA16(1, 1); SBAR;
    // P8: (1,0); stage B1 of u+3 -> db1; confirm tile u+2
    LDB_FB(pB1, 0);
    STG(LB, gB, 1, 1, u+3);
    VM4; SBAR; MFMA16(1, 0); SBAR;
  }
#undef STG
#undef LDA_FA
#undef LDB_FB
#undef MFMA16
#undef SBAR
#undef VM4

  #pragma unroll
  for (int m = 0; m < 8; ++m){
    const int gr0 = bm*256 + (m>>2)*128 + wrq*64 + (m&3)*16 + l4*4;
    #pragma unroll
    for (int n = 0; n < 4; ++n){
      const int gc = bn*256 + (n>>1)*128 + wcq*32 + (n&1)*16 + l15;
      const float bv = bias[gc];
      #pragma unroll
      for (int r2 = 0; r2 < 4; ++r2){
        const size_t off = (size_t)(gr0 + r2) * N + gc;
        float v = acc[m][n][r2] + bv;
        if (MODE == 0){
          ((u16*)out)[off] = f2bf(v);
        } else if (MODE == 1){
          const float a = 0.7978845608028654f * (v + 0.044715f * v * v * v);
          const float e = __expf(2.0f * a);
          const float th = (e - 1.0f) / (e + 1.0f);
          ((u16*)out)[off] = f2bf(0.5f * v * (1.0f + th));
        } else {
          float* op = (float*)out;
          op[off] += v;
        }
      }
    }
  }
}

// ---------------- transpose (B,L,ld) slice -> (B,H,64,L) per (b,h), bf16 ----------------
__global__ __launch_bounds__(256) void k_tr(const u16* __restrict__ Q, u16* __restrict__ Qt, int ld){
  __shared__ u16 Ls[64][65];
  const int tid = threadIdx.x;
  const int bh = blockIdx.y;
  const int b = bh >> 4, h = bh & 15;
  const int l0 = blockIdx.x * 64;
  #pragma unroll
  for (int i = 0; i < 16; ++i){
    const int id = i*256 + tid;
    const int lr = id >> 6, dc = id & 63;
    Ls[lr][dc] = Q[((size_t)b*4096 + l0 + lr)*ld + h*64 + dc];
  }
  __syncthreads();
  #pragma unroll
  for (int i = 0; i < 16; ++i){
    const int id = i*256 + tid;
    const int dr = id >> 6, lc = id & 63;
    Qt[((size_t)bh*64 + dr)*4096 + l0 + lc] = Ls[lc][dr];
  }
}

// ---------------- in-LDS radix-2 DIT FFT, N=4096, 256 threads ----------------
DEV void fft4096(float2* Z, const float2* tw, int tid, bool inv){
  for (int i = tid; i < 4096; i += 256){
    const int j = (int)(__brev((unsigned)i) >> 20);
    if (i < j){ float2 t = Z[i]; Z[i] = Z[j]; Z[j] = t; }
  }
  __syncthreads();
  for (int s = 1; s <= 12; ++s){
    const int half = 1 << (s - 1);
    for (int t = tid; t < 2048; t += 256){
      const int j = t & (half - 1);
      const int i0 = ((t >> (s-1)) << s) + j;
      const int i1 = i0 + half;
      float2 w = tw[j << (12 - s)];
      const float wy = inv ? -w.y : w.y;
      const float2 u = Z[i0], v = Z[i1];
      const float vr = v.x * w.x - v.y * wy;
      const float vi = v.x * wy + v.y * w.x;
      Z[i0] = make_float2(u.x + vr, u.y + vi);
      Z[i1] = make_float2(u.x - vr, u.y - vi);
    }
    __syncthreads();
  }
}

// ---------------- FFT of (q + i*k) per (b,h,d); accumulate S[f] = sum_d qf*conj(kf) ----------------
__global__ __launch_bounds__(256) void k_fftcorr(const u16* __restrict__ Qt, const u16* __restrict__ Kt,
                                                 float* __restrict__ S){
  __shared__ float2 Z[4096];      // 32 KB
  __shared__ float2 tw[2048];     // 16 KB
  const int tid = threadIdx.x;
  const int bh = blockIdx.x, dg = blockIdx.y;
  for (int k = tid; k < 2048; k += 256){
    float sn, cs;
    sincosf(-1.5339807878856412e-03f * (float)k, &sn, &cs);   // -2*pi/4096 * k
    tw[k] = make_float2(cs, sn);
  }
  float2 sa[16];
  #pragma unroll
  for (int j = 0; j < 16; ++j) sa[j] = make_float2(0.f, 0.f);
  __syncthreads();
  for (int dd = 0; dd < 16; ++dd){
    const int d = dg*16 + dd;
    const u16* q  = Qt + ((size_t)bh*64 + d) * 4096;
    const u16* kp = Kt + ((size_t)bh*64 + d) * 4096;
    for (int i = tid; i < 4096; i += 256)
      Z[i] = make_float2(bf2f(q[i]), bf2f(kp[i]));
    __syncthreads();
    fft4096(Z, tw, tid, false);
    #pragma unroll
    for (int j = 0; j < 16; ++j){
      const int f = j*256 + tid;
      const float2 a = Z[f];
      const float2 c = Z[(4096 - f) & 4095];
      const float qr = 0.5f * (a.x + c.x);
      const float qi = 0.5f * (a.y - c.y);
      const float kr = 0.5f * (a.y + c.y);
      const float ki = 0.5f * (c.x - a.x);
      sa[j].x += qr*kr + qi*ki;     // Re(qf * conj(kf))
      sa[j].y += qi*kr - qr*ki;     // Im(qf * conj(kf))
    }
    __syncthreads();
  }
  float* Sg = S + (size_t)bh * 8192;
  #pragma unroll
  for (int j = 0; j < 16; ++j){
    const int f = j*256 + tid;
    atomicAdd(&Sg[2*f + 0], sa[j].x);
    atomicAdd(&Sg[2*f + 1], sa[j].y);
  }
}

// ---------------- inverse FFT of S -> corr; softmax over L -> attn ----------------
__global__ __launch_bounds__(256) void k_isoftmax(const float* __restrict__ S, float* __restrict__ attn){
  __shared__ float2 Z[4096];
  __shared__ float2 tw[2048];
  __shared__ float red[4];
  __shared__ float bc;
  const int tid = threadIdx.x;
  const int bh = blockIdx.x;
  for (int k = tid; k < 2048; k += 256){
    float sn, cs;
    sincosf(-1.5339807878856412e-03f * (float)k, &sn, &cs);
    tw[k] = make_float2(cs, sn);
  }
  const float2* Sg = (const float2*)(S + (size_t)bh * 8192);
  for (int i = tid; i < 4096; i += 256) Z[i] = Sg[i];
  __syncthreads();
  fft4096(Z, tw, tid, true);          // unnormalized inverse
  const float scale = 1.0f / (4096.0f * 64.0f);   // 1/N (ifft) * 1/HD (mean over d)
  float cr[16];
  float lmax = -1e30f;
  #pragma unroll
  for (int j = 0; j < 16; ++j){
    const float c = Z[j*256 + tid].x * scale;
    cr[j] = c;
    lmax = fmaxf(lmax, c);
  }
  #pragma unroll
  for (int o = 32; o > 0; o >>= 1) lmax = fmaxf(lmax, __shfl_down(lmax, o));
  if ((tid & 63) == 0) red[tid >> 6] = lmax;
  __syncthreads();
  if (tid == 0) bc = fmaxf(fmaxf(red[0], red[1]), fmaxf(red[2], red[3]));
  __syncthreads();
  const float gmax = bc;
  float lsum = 0.f;
  #pragma unroll
  for (int j = 0; j < 16; ++j){ cr[j] = __expf(cr[j] - gmax); lsum += cr[j]; }
  #pragma unroll
  for (int o = 32; o > 0; o >>= 1) lsum += __shfl_down(lsum, o);
  if ((tid & 63) == 0) red[tid >> 6] = lsum;
  __syncthreads();
  if (tid == 0) bc = red[0] + red[1] + red[2] + red[3];
  __syncthreads();
  const float inv = 1.0f / bc;
  float* at = attn + (size_t)bh * 4096;
  #pragma unroll
  for (int j = 0; j < 16; ++j) at[j*256 + tid] = cr[j] * inv;
}

// ---------------- out[b,h,d] = sum_l attn[b,h,l] * V[b,l,h,d]; store lossy-transposed ----------------
__global__ __launch_bounds__(256) void k_av(const float* __restrict__ attn, const u16* __restrict__ V,
                                            float* __restrict__ oav, int ld){
  const int bh = blockIdx.x;
  const int b = bh >> 4, h = bh & 15;
  const int tid = threadIdx.x;
  const int d = tid & 63, lg = tid >> 6;
  const u16* vb = V + (size_t)b*4096*ld + h*64 + d;
  const float* at = attn + (size_t)bh * 4096;
  float acc = 0.f;
  for (int l = lg*1024; l < lg*1024 + 1024; ++l)
    acc += at[l] * bf2f(vb[(size_t)l * ld]);
  __shared__ float part[4][64];
  part[lg][d] = acc;
  __syncthreads();
  if (lg == 0)
    oav[(size_t)b*1024 + d*16 + h] = part[0][d] + part[1][d] + part[2][d] + part[3][d];  // flat idx = hd*H + h
}

// ---------------- proj = oav @ Wo^T + bo  (8 x 1024) ----------------
__global__ __launch_bounds__(256) void k_proj(const float* __restrict__ oav, const float* __restrict__ Wo,
                                              const float* __restrict__ bo, float* __restrict__ proj){
  const int b = blockIdx.x;
  const int o = blockIdx.y * 256 + threadIdx.x;
  __shared__ float xin[1024];
  for (int i = threadIdx.x; i < 1024; i += 256) xin[i] = oav[(size_t)b*1024 + i];
  __syncthreads();
  float acc = bo[o];
  const float4* wr = (const float4*)(Wo + (size_t)o * 1024);
  #pragma unroll 4
  for (int i = 0; i < 256; ++i){
    const float4 w4 = wr[i];
    acc += xin[4*i]*w4.x + xin[4*i+1]*w4.y + xin[4*i+2]*w4.z + xin[4*i+3]*w4.w;
  }
  proj[(size_t)b*1024 + o] = acc;
}

// ---------------- x1 = x + proj; x2 = x1 - movavg25(x1, zero-padded); write x2 to out ----------------
__global__ __launch_bounds__(256) void k_decomp(const float* __restrict__ x, const float* __restrict__ proj,
                                                float* __restrict__ out){
  const int row = blockIdx.x;           // b*4096 + l
  const int b = row >> 12, l = row & 4095;
  const int d = blockIdx.y * 256 + threadIdx.x;
  const float pv = proj[(size_t)b*1024 + d];
  const float* xb = x + (size_t)b * 4096 * 1024 + d;
  float wsum = 0.f; float cnt;
  if (l >= 12 && l < 4084){
    #pragma unroll
    for (int j = -12; j <= 12; ++j) wsum += xb[(size_t)(l + j) * 1024];
    cnt = 25.f;
  } else {
    cnt = 0.f;
    #pragma unroll
    for (int j = -12; j <= 12; ++j){
      const int ll = l + j;
      if (0 <= ll && ll < 4096){ wsum += xb[(size_t)ll * 1024]; cnt += 1.f; }
    }
  }
  const float xc = xb[(size_t)l * 1024];
  out[(size_t)row * 1024 + d] = xc + pv - (wsum + cnt * pv) * 0.04f;
}

extern "C" void kernel_launch(void* const* d_in, const int* in_sizes, int n_in,
                              void* d_out, int out_size, void* d_ws, size_t ws_size,
                              hipStream_t stream){
  const float* x    = (const float*)d_in[0];
  const float* ln1w = (const float*)d_in[1];
  const float* ln1b = (const float*)d_in[2];
  const float* Wq   = (const float*)d_in[3];
  const float* bq   = (const float*)d_in[4];
  const float* Wk   = (const float*)d_in[5];
  const float* bk   = (const float*)d_in[6];
  const float* Wv   = (const float*)d_in[7];
  const float* bv   = (const float*)d_in[8];
  const float* Wo   = (const float*)d_in[9];
  const float* bo   = (const float*)d_in[10];
  const float* ln2w = (const float*)d_in[11];
  const float* ln2b = (const float*)d_in[12];
  const float* W1   = (const float*)d_in[13];
  const float* b1   = (const float*)d_in[14];
  const float* W2   = (const float*)d_in[15];
  const float* b2   = (const float*)d_in[16];
  float* out = (float*)d_out;

  char* ws = (char*)d_ws;
  // Region A [0, 256MB): QKV (192MB) + Qt (64MB) early; H1 (32768x4096 bf16, 256MB) late.
  u16* QKV  = (u16*)(ws + 0);                 // (32768, 3072) bf16: cols 0-1023 Q, 1024-2047 K, 2048-3071 V
  u16* Qt   = (u16*)(ws + 201326592);
  u16* H1   = (u16*)(ws + 0);
  // Slot B [256MB, 320MB): Y(ln1) -> Kt -> Y2(ln2), 64MB each, strictly sequential lifetimes.
  u16* Y    = (u16*)(ws + 268435456);
  u16* Kt   = (u16*)(ws + 268435456);
  float* S    = (float*)(ws + 335544320);     // B*H*4096 complex f32 = 4 MB
  float* attn = (float*)(ws + 339738624);     // 2 MB
  float* oav  = (float*)(ws + 341835776);     // 32 KB
  float* proj = (float*)(ws + 341868544);     // 32 KB
  float* bqkv = (float*)(ws + 341901312);     // 12 KB (pad to 16K)
  u16* Wqkvb  = (u16*)(ws + 341917696);       // 6 MB
  u16* W1b    = (u16*)(ws + 348209152);       // 8 MB
  u16* W2b    = (u16*)(ws + 356597760);       // 8 MB -> ends ~365 MB

  // weights -> bf16 (Wq/Wk/Wv concatenated row-wise into one (3072,1024) matrix)
  k_cvt<<<4096, 256, 0, stream>>>(Wq, Wqkvb,           1048576);
  k_cvt<<<4096, 256, 0, stream>>>(Wk, Wqkvb + 1048576, 1048576);
  k_cvt<<<4096, 256, 0, stream>>>(Wv, Wqkvb + 2097152, 1048576);
  k_cvt<<<16384, 256, 0, stream>>>(W1, W1b, 4194304);
  k_cvt<<<16384, 256, 0, stream>>>(W2, W2b, 4194304);
  k_cat3<<<4, 256, 0, stream>>>(bq, bk, bv, bqkv);

  // y = LN1(x)
  k_ln<<<32768, 256, 0, stream>>>(x, ln1w, ln1b, Y);

  // fused QKV projection: (32768 x 3072) = Y @ Wqkv^T + bqkv  (grid = 128*12, %8==0)
  k_gemm4<0><<<1536, 512, 0, stream>>>(Y, Wqkvb, bqkv, QKV, 32768, 3072, 1024);

  // transpose to (B,H,64,L) for contiguous FFT columns
  k_tr<<<dim3(64, 128), 256, 0, stream>>>(QKV,        Qt, 3072);
  k_tr<<<dim3(64, 128), 256, 0, stream>>>(QKV + 1024, Kt, 3072);

  // S[f] = sum_d rfft(Q_d) * conj(rfft(K_d))   (full Hermitian spectrum)
  hipMemsetAsync(S, 0, 4194304, stream);
  k_fftcorr<<<dim3(128, 4), 256, 0, stream>>>(Qt, Kt, S);
  // corr = ifft(S)/(N*HD); attn = softmax(corr)
  k_isoftmax<<<128, 256, 0, stream>>>(S, attn);
  // out_av[b, hd*16+h] = sum_l attn * V
  k_av<<<128, 256, 0, stream>>>(attn, QKV + 2048, oav, 3072);
  // proj = oav @ Wo^T + bo
  k_proj<<<dim3(8, 4), 256, 0, stream>>>(oav, Wo, bo, proj);

  // x2 = (x + proj) - movavg25(x + proj)  -> d_out
  k_decomp<<<dim3(32768, 4), 256, 0, stream>>>(x, proj, out);

  // y2 = LN2(x2)
  k_ln<<<32768, 256, 0, stream>>>(out, ln2w, ln2b, Y);

  // MLP: h1 = gelu(y2 @ W1^T + b1);  d_out = x2 + h1 @ W2^T + b2
  k_gemm4<1><<<2048, 512, 0, stream>>>(Y, W1b, b1, H1, 32768, 4096, 1024);
  k_gemm4<2><<<512, 512, 0, stream>>>(H1, W2b, b2, out, 32768, 1024, 4096);
}

// Round 5
// 1647.271 us; speedup vs baseline: 1.2073x; 1.1251x over previous
//
#include <hip/hip_runtime.h>

#define DEV __device__ __forceinline__

typedef __attribute__((ext_vector_type(8))) short bf16x8;
typedef __attribute__((ext_vector_type(4))) float f32x4;
typedef unsigned short u16;
typedef __attribute__((address_space(1))) const void* gvp;
typedef __attribute__((address_space(3))) void* svp;

DEV u16 f2bf(float f){
  unsigned u = __float_as_uint(f);
  u = (u + 0x7FFFu + ((u >> 16) & 1u)) >> 16;
  return (u16)u;
}
DEV float bf2f(u16 v){ return __uint_as_float(((unsigned)v) << 16); }

// ---------------- convert f32 -> bf16 ----------------
__global__ void k_cvt(const float* __restrict__ s, u16* __restrict__ d, int n){
  int i = blockIdx.x * 256 + threadIdx.x;
  if (i < n) d[i] = f2bf(s[i]);
}

// ---------------- concat 3 bias vectors (1024 each) ----------------
__global__ void k_cat3(const float* __restrict__ a, const float* __restrict__ b,
                       const float* __restrict__ c, float* __restrict__ o){
  int i = blockIdx.x * 256 + threadIdx.x;
  if (i < 1024){ o[i] = a[i]; o[1024 + i] = b[i]; o[2048 + i] = c[i]; }
}

// ---------------- layernorm over D=1024, bf16 out ----------------
__global__ __launch_bounds__(256) void k_ln(const float* __restrict__ x, const float* __restrict__ w,
                                            const float* __restrict__ b, u16* __restrict__ y){
  const int row = blockIdx.x;
  const int tid = threadIdx.x;
  const float4 v = ((const float4*)(x + (size_t)row * 1024))[tid];
  float s1 = v.x + v.y + v.z + v.w;
  float s2 = v.x*v.x + v.y*v.y + v.z*v.z + v.w*v.w;
  #pragma unroll
  for (int o = 32; o > 0; o >>= 1){ s1 += __shfl_down(s1, o); s2 += __shfl_down(s2, o); }
  __shared__ float r1[4], r2[4];
  __shared__ float mu_s, rs_s;
  const int wv = tid >> 6;
  if ((tid & 63) == 0){ r1[wv] = s1; r2[wv] = s2; }
  __syncthreads();
  if (tid == 0){
    float t1 = r1[0]+r1[1]+r1[2]+r1[3], t2 = r2[0]+r2[1]+r2[2]+r2[3];
    float mu = t1 * (1.0f/1024.0f);
    float var = t2 * (1.0f/1024.0f) - mu*mu;
    mu_s = mu; rs_s = rsqrtf(var + 1e-6f);
  }
  __syncthreads();
  const float mu = mu_s, rs = rs_s;
  const float4 wv4 = ((const float4*)w)[tid];
  const float4 bv4 = ((const float4*)b)[tid];
  ushort4 o4;
  o4.x = f2bf((v.x-mu)*rs*wv4.x + bv4.x);
  o4.y = f2bf((v.y-mu)*rs*wv4.y + bv4.y);
  o4.z = f2bf((v.z-mu)*rs*wv4.z + bv4.z);
  o4.w = f2bf((v.w-mu)*rs*wv4.w + bv4.w);
  ((ushort4*)(y + (size_t)row*1024))[tid] = o4;
}

// ---------------- 256x256 tile, BK=64, 8-phase counted-vmcnt bf16 MFMA GEMM ----------------
// asm ds_read_b128 (opaque to waitcnt pass) + explicit lgkmcnt(0)+sched_barrier (rule #18);
// vmcnt(4) only at P4/P8. Staging calendar identical to (verified) R4 ledger.
// MODE 0: bf16 store. MODE 1: gelu then bf16 store. MODE 2: f32 out[off] += v
template<int MODE>
__launch_bounds__(512, 2)
__global__ void k_gemm5(const u16* __restrict__ A, const u16* __restrict__ Bw,
                        const float* __restrict__ bias, void* __restrict__ out,
                        int M, int N, int K)
{
  __shared__ __align__(16) u16 LA[2][16384];   // [db][256 rows x 64 k] = 2 x 32KB
  __shared__ __align__(16) u16 LB[2][16384];
  const int tid = threadIdx.x;
  const int wave = tid >> 6, lane = tid & 63;
  const int l15 = lane & 15, l4 = lane >> 4;
  const int wrq = wave >> 2, wcq = wave & 3;   // wave pos inside a 128x128 quadrant
  (void)M;

  // XCD-bijective swizzle (grid % 8 == 0 for all our shapes), bm-major (bn inner)
  const int nwg = gridDim.x;
  const int q8 = nwg >> 3;
  const int wg = (blockIdx.x & 7) * q8 + (blockIdx.x >> 3);
  const int NBN = N >> 8;
  const int bm = wg / NBN, bn = wg % NBN;
  const int NT = K >> 6, NI = NT >> 1;

  // ---- staging geometry: linear LDS dest; inverse-swizzled global source ----
  const int sr8 = lane >> 3;
  const int sch8 = ((lane & 7) ^ (sr8 & 7)) * 8;           // u16 units
  const u16* gA = A  + ((size_t)(bm*256 + wave*16 + sr8)) * K + sch8;
  const u16* gB = Bw + ((size_t)(bn*256 + wave*16 + sr8)) * K + sch8;
  const size_t gH = (size_t)128 * K;                        // +128 rows (half select)
  const size_t gJ = (size_t)8 * K;                          // +8 rows (instr j=1)
  const int lbase = wave * 1024;                            // u16; + half*8192 + j*512

  // ---- asm ds_read bases (byte offsets in LDS); k-XOR baked into second base ----
  const unsigned swzb = (unsigned)((l4 ^ (l15 & 7)) * 16);
  const unsigned uA0  = (unsigned)(uintptr_t)&LA[0][0] + (unsigned)((wrq*64 + l15)*128) + swzb;
  const unsigned uB0  = (unsigned)(uintptr_t)&LB[0][0] + (unsigned)((wcq*32 + l15)*128) + swzb;
  const unsigned uA0x = uA0 ^ 64u, uB0x = uB0 ^ 64u;
  const unsigned uA1  = uA0 + 32768u, uA1x = uA0x + 32768u;
  const unsigned uB1  = uB0 + 32768u, uB1x = uB0x + 32768u;

  f32x4 acc[8][4];
  const f32x4 z4 = {0.f, 0.f, 0.f, 0.f};
  #pragma unroll
  for (int m = 0; m < 8; ++m)
    #pragma unroll
    for (int n = 0; n < 4; ++n) acc[m][n] = z4;

#define DSR(dst, base, OFF) asm volatile("ds_read_b128 %0, %1 offset:" #OFF : "=v"(dst) : "v"(base))

// A quad 0 (rows 0-127): frag(mm,kk) at offset mm*2048, kk via base (^64)
#define LDA_Q0(b0, b1) do{ \
  DSR(fa[0], b0, 0);    DSR(fa[1], b1, 0); \
  DSR(fa[2], b0, 2048); DSR(fa[3], b1, 2048); \
  DSR(fa[4], b0, 4096); DSR(fa[5], b1, 4096); \
  DSR(fa[6], b0, 6144); DSR(fa[7], b1, 6144); }while(0)
// A quad 1 (rows 128-255): +16384 bytes
#define LDA_Q1(b0, b1) do{ \
  DSR(fa[0], b0, 16384); DSR(fa[1], b1, 16384); \
  DSR(fa[2], b0, 18432); DSR(fa[3], b1, 18432); \
  DSR(fa[4], b0, 20480); DSR(fa[5], b1, 20480); \
  DSR(fa[6], b0, 22528); DSR(fa[7], b1, 22528); }while(0)
#define LDB_Q0(dst, b0, b1) do{ \
  DSR(dst[0], b0, 0);    DSR(dst[1], b1, 0); \
  DSR(dst[2], b0, 2048); DSR(dst[3], b1, 2048); }while(0)
#define LDB_Q1(dst, b0, b1) do{ \
  DSR(dst[0], b0, 16384); DSR(dst[1], b1, 16384); \
  DSR(dst[2], b0, 18432); DSR(dst[3], b1, 18432); }while(0)

#define STG(LD, G, DB, HALF, TK) do{ \
    const int tk_ = (TK) < NT ? (TK) : NT - 1; \
    const u16* g_ = (G) + (size_t)tk_ * 64 + (size_t)(HALF) * gH; \
    u16* l_ = &LD[DB][lbase + (HALF) * 8192]; \
    __builtin_amdgcn_global_load_lds((gvp)g_,        (svp)l_,        16, 0, 0); \
    __builtin_amdgcn_global_load_lds((gvp)(g_ + gJ), (svp)(l_ + 512),16, 0, 0); \
  }while(0)

#define MFMA16(QA, QB, FB) do{ \
    __builtin_amdgcn_s_setprio(1); \
    _Pragma("unroll") for (int kk = 0; kk < 2; ++kk) \
    _Pragma("unroll") for (int mm = 0; mm < 4; ++mm) \
    _Pragma("unroll") for (int nn = 0; nn < 2; ++nn) \
      acc[(QA)*4+mm][(QB)*2+nn] = __builtin_amdgcn_mfma_f32_16x16x32_bf16( \
          fa[mm*2+kk], FB[nn*2+kk], acc[(QA)*4+mm][(QB)*2+nn], 0, 0, 0); \
    __builtin_amdgcn_s_setprio(0); \
  }while(0)

#define SBAR  __builtin_amdgcn_s_barrier()
#define SB0   __builtin_amdgcn_sched_barrier(0)
#define LGKM0 do{ asm volatile("s_waitcnt lgkmcnt(0)" ::: "memory"); SB0; }while(0)
#define LGKM8 asm volatile("s_waitcnt lgkmcnt(8)" ::: "memory")
#define VM4   asm volatile("s_waitcnt vmcnt(4)" ::: "memory")

  // ---- prologue: tile0 (all 4 regions)->db0, A0(1)+B1(1)->db1; confirm tile0 ----
  STG(LA, gA, 0, 0, 0); STG(LA, gA, 0, 1, 0);
  STG(LB, gB, 0, 0, 0); STG(LB, gB, 0, 1, 0);
  STG(LA, gA, 1, 0, 1);
  STG(LB, gB, 1, 1, 1);
  VM4; SBAR;

  for (int it = 0; it < NI; ++it){
    const int u = 2 * it;
    bf16x8 fa[8], fbA[4], fbB[4];
    // ---- tile u in db0 ----
    // P1: (0,0); stage A1,B0 of u+1 -> db1
    LDB_Q0(fbA, uB0, uB0x);
    LDA_Q0(uA0, uA0x);
    STG(LA, gA, 1, 1, u+1); STG(LB, gB, 1, 0, u+1);
    LGKM8;
    SBAR; LGKM0; MFMA16(0, 0, fbA); SB0; SBAR;
    // P2: (0,1)
    LDB_Q1(fbB, uB0, uB0x);
    SBAR; LGKM0; MFMA16(0, 1, fbB); SB0; SBAR;
    // P3: (1,1); stage A0 of u+2 -> db0
    LDA_Q1(uA0, uA0x);
    STG(LA, gA, 0, 0, u+2);
    SBAR; LGKM0; MFMA16(1, 1, fbB); SB0; SBAR;
    // P4: (1,0) — fbA reused from P1, no ds_reads; stage B1 of u+2 -> db0; confirm u+1
    STG(LB, gB, 0, 1, u+2);
    VM4; SBAR; SB0; MFMA16(1, 0, fbA); SB0; SBAR;
    // ---- tile u+1 in db1 ----
    // P5: (0,0); stage A1,B0 of u+2 -> db0
    LDB_Q0(fbA, uB1, uB1x);
    LDA_Q0(uA1, uA1x);
    STG(LA, gA, 0, 1, u+2); STG(LB, gB, 0, 0, u+2);
    LGKM8;
    SBAR; LGKM0; MFMA16(0, 0, fbA); SB0; SBAR;
    // P6: (0,1)
    LDB_Q1(fbB, uB1, uB1x);
    SBAR; LGKM0; MFMA16(0, 1, fbB); SB0; SBAR;
    // P7: (1,1); stage A0 of u+3 -> db1
    LDA_Q1(uA1, uA1x);
    STG(LA, gA, 1, 0, u+3);
    SBAR; LGKM0; MFMA16(1, 1, fbB); SB0; SBAR;
    // P8: (1,0) — fbA reused from P5; stage B1 of u+3 -> db1; confirm u+2
    STG(LB, gB, 1, 1, u+3);
    VM4; SBAR; SB0; MFMA16(1, 0, fbA); SB0; SBAR;
  }
#undef DSR
#undef LDA_Q0
#undef LDA_Q1
#undef LDB_Q0
#undef LDB_Q1
#undef STG
#undef MFMA16
#undef SBAR
#undef SB0
#undef LGKM0
#undef LGKM8
#undef VM4

  #pragma unroll
  for (int m = 0; m < 8; ++m){
    const int gr0 = bm*256 + (m>>2)*128 + wrq*64 + (m&3)*16 + l4*4;
    #pragma unroll
    for (int n = 0; n < 4; ++n){
      const int gc = bn*256 + (n>>1)*128 + wcq*32 + (n&1)*16 + l15;
      const float bv = bias[gc];
      #pragma unroll
      for (int r2 = 0; r2 < 4; ++r2){
        const size_t off = (size_t)(gr0 + r2) * N + gc;
        float v = acc[m][n][r2] + bv;
        if (MODE == 0){
          ((u16*)out)[off] = f2bf(v);
        } else if (MODE == 1){
          const float a = 0.7978845608028654f * (v + 0.044715f * v * v * v);
          const float e = __expf(2.0f * a);
          const float th = (e - 1.0f) / (e + 1.0f);
          ((u16*)out)[off] = f2bf(0.5f * v * (1.0f + th));
        } else {
          float* op = (float*)out;
          op[off] += v;
        }
      }
    }
  }
}

// ---------------- transpose (B,L,ld) slice -> (B,H,64,L) per (b,h), bf16 ----------------
__global__ __launch_bounds__(256) void k_tr(const u16* __restrict__ Q, u16* __restrict__ Qt, int ld){
  __shared__ u16 Ls[64][65];
  const int tid = threadIdx.x;
  const int bh = blockIdx.y;
  const int b = bh >> 4, h = bh & 15;
  const int l0 = blockIdx.x * 64;
  #pragma unroll
  for (int i = 0; i < 16; ++i){
    const int id = i*256 + tid;
    const int lr = id >> 6, dc = id & 63;
    Ls[lr][dc] = Q[((size_t)b*4096 + l0 + lr)*ld + h*64 + dc];
  }
  __syncthreads();
  #pragma unroll
  for (int i = 0; i < 16; ++i){
    const int id = i*256 + tid;
    const int dr = id >> 6, lc = id & 63;
    Qt[((size_t)bh*64 + dr)*4096 + l0 + lc] = Ls[lc][dr];
  }
}

// ---------------- in-LDS radix-2 DIT FFT, N=4096, 256 threads ----------------
DEV void fft4096(float2* Z, const float2* tw, int tid, bool inv){
  for (int i = tid; i < 4096; i += 256){
    const int j = (int)(__brev((unsigned)i) >> 20);
    if (i < j){ float2 t = Z[i]; Z[i] = Z[j]; Z[j] = t; }
  }
  __syncthreads();
  for (int s = 1; s <= 12; ++s){
    const int half = 1 << (s - 1);
    for (int t = tid; t < 2048; t += 256){
      const int j = t & (half - 1);
      const int i0 = ((t >> (s-1)) << s) + j;
      const int i1 = i0 + half;
      float2 w = tw[j << (12 - s)];
      const float wy = inv ? -w.y : w.y;
      const float2 u = Z[i0], v = Z[i1];
      const float vr = v.x * w.x - v.y * wy;
      const float vi = v.x * wy + v.y * w.x;
      Z[i0] = make_float2(u.x + vr, u.y + vi);
      Z[i1] = make_float2(u.x - vr, u.y - vi);
    }
    __syncthreads();
  }
}

// ---------------- FFT of (q + i*k) per (b,h,d); accumulate S[f] = sum_d qf*conj(kf) ----------------
__global__ __launch_bounds__(256) void k_fftcorr(const u16* __restrict__ Qt, const u16* __restrict__ Kt,
                                                 float* __restrict__ S){
  __shared__ float2 Z[4096];      // 32 KB
  __shared__ float2 tw[2048];     // 16 KB
  const int tid = threadIdx.x;
  const int bh = blockIdx.x, dg = blockIdx.y;
  for (int k = tid; k < 2048; k += 256){
    float sn, cs;
    sincosf(-1.5339807878856412e-03f * (float)k, &sn, &cs);   // -2*pi/4096 * k
    tw[k] = make_float2(cs, sn);
  }
  float2 sa[16];
  #pragma unroll
  for (int j = 0; j < 16; ++j) sa[j] = make_float2(0.f, 0.f);
  __syncthreads();
  for (int dd = 0; dd < 8; ++dd){
    const int d = dg*8 + dd;
    const u16* q  = Qt + ((size_t)bh*64 + d) * 4096;
    const u16* kp = Kt + ((size_t)bh*64 + d) * 4096;
    for (int i = tid; i < 4096; i += 256)
      Z[i] = make_float2(bf2f(q[i]), bf2f(kp[i]));
    __syncthreads();
    fft4096(Z, tw, tid, false);
    #pragma unroll
    for (int j = 0; j < 16; ++j){
      const int f = j*256 + tid;
      const float2 a = Z[f];
      const float2 c = Z[(4096 - f) & 4095];
      const float qr = 0.5f * (a.x + c.x);
      const float qi = 0.5f * (a.y - c.y);
      const float kr = 0.5f * (a.y + c.y);
      const float ki = 0.5f * (c.x - a.x);
      sa[j].x += qr*kr + qi*ki;     // Re(qf * conj(kf))
      sa[j].y += qi*kr - qr*ki;     // Im(qf * conj(kf))
    }
    __syncthreads();
  }
  float* Sg = S + (size_t)bh * 8192;
  #pragma unroll
  for (int j = 0; j < 16; ++j){
    const int f = j*256 + tid;
    atomicAdd(&Sg[2*f + 0], sa[j].x);
    atomicAdd(&Sg[2*f + 1], sa[j].y);
  }
}

// ---------------- inverse FFT of S -> corr; softmax over L -> attn ----------------
__global__ __launch_bounds__(256) void k_isoftmax(const float* __restrict__ S, float* __restrict__ attn){
  __shared__ float2 Z[4096];
  __shared__ float2 tw[2048];
  __shared__ float red[4];
  __shared__ float bc;
  const int tid = threadIdx.x;
  const int bh = blockIdx.x;
  for (int k = tid; k < 2048; k += 256){
    float sn, cs;
    sincosf(-1.5339807878856412e-03f * (float)k, &sn, &cs);
    tw[k] = make_float2(cs, sn);
  }
  const float2* Sg = (const float2*)(S + (size_t)bh * 8192);
  for (int i = tid; i < 4096; i += 256) Z[i] = Sg[i];
  __syncthreads();
  fft4096(Z, tw, tid, true);          // unnormalized inverse
  const float scale = 1.0f / (4096.0f * 64.0f);   // 1/N (ifft) * 1/HD (mean over d)
  float cr[16];
  float lmax = -1e30f;
  #pragma unroll
  for (int j = 0; j < 16; ++j){
    const float c = Z[j*256 + tid].x * scale;
    cr[j] = c;
    lmax = fmaxf(lmax, c);
  }
  #pragma unroll
  for (int o = 32; o > 0; o >>= 1) lmax = fmaxf(lmax, __shfl_down(lmax, o));
  if ((tid & 63) == 0) red[tid >> 6] = lmax;
  __syncthreads();
  if (tid == 0) bc = fmaxf(fmaxf(red[0], red[1]), fmaxf(red[2], red[3]));
  __syncthreads();
  const float gmax = bc;
  float lsum = 0.f;
  #pragma unroll
  for (int j = 0; j < 16; ++j){ cr[j] = __expf(cr[j] - gmax); lsum += cr[j]; }
  #pragma unroll
  for (int o = 32; o > 0; o >>= 1) lsum += __shfl_down(lsum, o);
  if ((tid & 63) == 0) red[tid >> 6] = lsum;
  __syncthreads();
  if (tid == 0) bc = red[0] + red[1] + red[2] + red[3];
  __syncthreads();
  const float inv = 1.0f / bc;
  float* at = attn + (size_t)bh * 4096;
  #pragma unroll
  for (int j = 0; j < 16; ++j) at[j*256 + tid] = cr[j] * inv;
}

// ---------------- out[b,h,d] = sum_l attn[b,h,l] * V[b,l,h,d]; store lossy-transposed ----------------
__global__ __launch_bounds__(256) void k_av(const float* __restrict__ attn, const u16* __restrict__ V,
                                            float* __restrict__ oav, int ld){
  const int bh = blockIdx.x;
  const int b = bh >> 4, h = bh & 15;
  const int tid = threadIdx.x;
  const int d = tid & 63, lg = tid >> 6;
  const u16* vb = V + (size_t)b*4096*ld + h*64 + d;
  const float* at = attn + (size_t)bh * 4096;
  float acc = 0.f;
  for (int l = lg*1024; l < lg*1024 + 1024; ++l)
    acc += at[l] * bf2f(vb[(size_t)l * ld]);
  __shared__ float part[4][64];
  part[lg][d] = acc;
  __syncthreads();
  if (lg == 0)
    oav[(size_t)b*1024 + d*16 + h] = part[0][d] + part[1][d] + part[2][d] + part[3][d];  // flat idx = hd*H + h
}

// ---------------- proj = oav @ Wo^T + bo  (8 x 1024) ----------------
__global__ __launch_bounds__(256) void k_proj(const float* __restrict__ oav, const float* __restrict__ Wo,
                                              const float* __restrict__ bo, float* __restrict__ proj){
  const int b = blockIdx.x;
  const int o = blockIdx.y * 256 + threadIdx.x;
  __shared__ float xin[1024];
  for (int i = threadIdx.x; i < 1024; i += 256) xin[i] = oav[(size_t)b*1024 + i];
  __syncthreads();
  float acc = bo[o];
  const float4* wr = (const float4*)(Wo + (size_t)o * 1024);
  #pragma unroll 4
  for (int i = 0; i < 256; ++i){
    const float4 w4 = wr[i];
    acc += xin[4*i]*w4.x + xin[4*i+1]*w4.y + xin[4*i+2]*w4.z + xin[4*i+3]*w4.w;
  }
  proj[(size_t)b*1024 + o] = acc;
}

// ---------------- x1 = x + proj; x2 = x1 - movavg25(x1, zero-padded); write x2 to out ----------------
__global__ __launch_bounds__(256) void k_decomp(const float* __restrict__ x, const float* __restrict__ proj,
                                                float* __restrict__ out){
  const int row = blockIdx.x;           // b*4096 + l
  const int b = row >> 12, l = row & 4095;
  const int d = blockIdx.y * 256 + threadIdx.x;
  const float pv = proj[(size_t)b*1024 + d];
  const float* xb = x + (size_t)b * 4096 * 1024 + d;
  float wsum = 0.f; float cnt;
  if (l >= 12 && l < 4084){
    #pragma unroll
    for (int j = -12; j <= 12; ++j) wsum += xb[(size_t)(l + j) * 1024];
    cnt = 25.f;
  } else {
    cnt = 0.f;
    #pragma unroll
    for (int j = -12; j <= 12; ++j){
      const int ll = l + j;
      if (0 <= ll && ll < 4096){ wsum += xb[(size_t)ll * 1024]; cnt += 1.f; }
    }
  }
  const float xc = xb[(size_t)l * 1024];
  out[(size_t)row * 1024 + d] = xc + pv - (wsum + cnt * pv) * 0.04f;
}

extern "C" void kernel_launch(void* const* d_in, const int* in_sizes, int n_in,
                              void* d_out, int out_size, void* d_ws, size_t ws_size,
                              hipStream_t stream){
  const float* x    = (const float*)d_in[0];
  const float* ln1w = (const float*)d_in[1];
  const float* ln1b = (const float*)d_in[2];
  const float* Wq   = (const float*)d_in[3];
  const float* bq   = (const float*)d_in[4];
  const float* Wk   = (const float*)d_in[5];
  const float* bk   = (const float*)d_in[6];
  const float* Wv   = (const float*)d_in[7];
  const float* bv   = (const float*)d_in[8];
  const float* Wo   = (const float*)d_in[9];
  const float* bo   = (const float*)d_in[10];
  const float* ln2w = (const float*)d_in[11];
  const float* ln2b = (const float*)d_in[12];
  const float* W1   = (const float*)d_in[13];
  const float* b1   = (const float*)d_in[14];
  const float* W2   = (const float*)d_in[15];
  const float* b2   = (const float*)d_in[16];
  float* out = (float*)d_out;

  char* ws = (char*)d_ws;
  // Region A [0, 256MB): QKV (192MB) + Qt (64MB) early; H1 (32768x4096 bf16, 256MB) late.
  u16* QKV  = (u16*)(ws + 0);                 // (32768, 3072) bf16: cols 0-1023 Q, 1024-2047 K, 2048-3071 V
  u16* Qt   = (u16*)(ws + 201326592);
  u16* H1   = (u16*)(ws + 0);
  // Slot B [256MB, 320MB): Y(ln1) -> Kt -> Y2(ln2), 64MB each, strictly sequential lifetimes.
  u16* Y    = (u16*)(ws + 268435456);
  u16* Kt   = (u16*)(ws + 268435456);
  float* S    = (float*)(ws + 335544320);     // B*H*4096 complex f32 = 4 MB
  float* attn = (float*)(ws + 339738624);     // 2 MB
  float* oav  = (float*)(ws + 341835776);     // 32 KB
  float* proj = (float*)(ws + 341868544);     // 32 KB
  float* bqkv = (float*)(ws + 341901312);     // 12 KB (pad to 16K)
  u16* Wqkvb  = (u16*)(ws + 341917696);       // 6 MB
  u16* W1b    = (u16*)(ws + 348209152);       // 8 MB
  u16* W2b    = (u16*)(ws + 356597760);       // 8 MB -> ends ~365 MB

  // weights -> bf16 (Wq/Wk/Wv concatenated row-wise into one (3072,1024) matrix)
  k_cvt<<<4096, 256, 0, stream>>>(Wq, Wqkvb,           1048576);
  k_cvt<<<4096, 256, 0, stream>>>(Wk, Wqkvb + 1048576, 1048576);
  k_cvt<<<4096, 256, 0, stream>>>(Wv, Wqkvb + 2097152, 1048576);
  k_cvt<<<16384, 256, 0, stream>>>(W1, W1b, 4194304);
  k_cvt<<<16384, 256, 0, stream>>>(W2, W2b, 4194304);
  k_cat3<<<4, 256, 0, stream>>>(bq, bk, bv, bqkv);

  // y = LN1(x)
  k_ln<<<32768, 256, 0, stream>>>(x, ln1w, ln1b, Y);

  // fused QKV projection: (32768 x 3072) = Y @ Wqkv^T + bqkv  (grid = 128*12, %8==0)
  k_gemm5<0><<<1536, 512, 0, stream>>>(Y, Wqkvb, bqkv, QKV, 32768, 3072, 1024);

  // transpose to (B,H,64,L) for contiguous FFT columns
  k_tr<<<dim3(64, 128), 256, 0, stream>>>(QKV,        Qt, 3072);
  k_tr<<<dim3(64, 128), 256, 0, stream>>>(QKV + 1024, Kt, 3072);

  // S[f] = sum_d rfft(Q_d) * conj(rfft(K_d))   (full Hermitian spectrum)
  hipMemsetAsync(S, 0, 4194304, stream);
  k_fftcorr<<<dim3(128, 8), 256, 0, stream>>>(Qt, Kt, S);
  // corr = ifft(S)/(N*HD); attn = softmax(corr)
  k_isoftmax<<<128, 256, 0, stream>>>(S, attn);
  // out_av[b, hd*16+h] = sum_l attn * V
  k_av<<<128, 256, 0, stream>>>(attn, QKV + 2048, oav, 3072);
  // proj = oav @ Wo^T + bo
  k_proj<<<dim3(8, 4), 256, 0, stream>>>(oav, Wo, bo, proj);

  // x2 = (x + proj) - movavg25(x + proj)  -> d_out
  k_decomp<<<dim3(32768, 4), 256, 0, stream>>>(x, proj, out);

  // y2 = LN2(x2)
  k_ln<<<32768, 256, 0, stream>>>(out, ln2w, ln2b, Y);

  // MLP: h1 = gelu(y2 @ W1^T + b1);  d_out = x2 + h1 @ W2^T + b2
  k_gemm5<1><<<2048, 512, 0, stream>>>(Y, W1b, b1, H1, 32768, 4096, 1024);
  k_gemm5<2><<<512, 512, 0, stream>>>(H1, W2b, b2, out, 32768, 1024, 4096);
}